// Round 1
// baseline (8355.534 us; speedup 1.0000x reference)
//
#include <hip/hip_runtime.h>
#include <hip/hip_bf16.h>

#define S_LEN 1024
#define B_SZ  4
#define E_SZ  1024
#define H_CNT 16
#define D_HD  64
// N1 = B*H*S*D = number of elements in one Q/K/V component
#define N1 (B_SZ * H_CNT * S_LEN * D_HD)

// ---------------------------------------------------------------------------
// Kernel 1: complex linear projection for Q/K/V.
//   x: [S,B,E] fp32 (row m = s*B + b), W: [E,E] fp32 (torch [out,in]), b: [E]
//   y = x @ W^T + b  (complex), output stored bf16 in [B,H,S,D] layout.
// grid (E/64, (S*B)/64), block 256 (16x16 threads, 4x4 microtile)
// ---------------------------------------------------------------------------
__global__ __launch_bounds__(256) void cproj_qkv(
    const float* __restrict__ xr, const float* __restrict__ xi,
    const float* __restrict__ wr_, const float* __restrict__ wi_,
    const float* __restrict__ br_, const float* __restrict__ bi_,
    __hip_bfloat16* __restrict__ yr, __hip_bfloat16* __restrict__ yi)
{
    __shared__ float sxr[64][17], sxi[64][17], swr[64][17], swi[64][17];
    const int n0 = blockIdx.x * 64;
    const int m0 = blockIdx.y * 64;
    const int tid = threadIdx.x;
    const int tx = tid & 15, ty = tid >> 4;
    const int lrow = tid >> 4, lcol = tid & 15;

    float accr[4][4] = {}, acci[4][4] = {};

    for (int k0 = 0; k0 < E_SZ; k0 += 16) {
#pragma unroll
        for (int i = 0; i < 4; ++i) {
            int r = lrow + 16 * i;
            sxr[r][lcol] = xr[(size_t)(m0 + r) * E_SZ + k0 + lcol];
            sxi[r][lcol] = xi[(size_t)(m0 + r) * E_SZ + k0 + lcol];
            swr[r][lcol] = wr_[(size_t)(n0 + r) * E_SZ + k0 + lcol];
            swi[r][lcol] = wi_[(size_t)(n0 + r) * E_SZ + k0 + lcol];
        }
        __syncthreads();
#pragma unroll
        for (int kk = 0; kk < 16; ++kk) {
            float ar[4], ai[4], brg[4], big[4];
#pragma unroll
            for (int i = 0; i < 4; ++i) {
                ar[i]  = sxr[ty + 16 * i][kk];
                ai[i]  = sxi[ty + 16 * i][kk];
                brg[i] = swr[tx + 16 * i][kk];
                big[i] = swi[tx + 16 * i][kk];
            }
#pragma unroll
            for (int i = 0; i < 4; ++i)
#pragma unroll
                for (int j = 0; j < 4; ++j) {
                    accr[i][j] += ar[i] * brg[j] - ai[i] * big[j];
                    acci[i][j] += ar[i] * big[j] + ai[i] * brg[j];
                }
        }
        __syncthreads();
    }
#pragma unroll
    for (int i = 0; i < 4; ++i) {
        int m = m0 + ty + 16 * i;
        int s = m >> 2;   // m = s*B + b
        int b = m & 3;
#pragma unroll
        for (int j = 0; j < 4; ++j) {
            int n = n0 + tx + 16 * j;
            int h = n >> 6, d = n & 63;
            float vr = accr[i][j] + br_[n];
            float vi = acci[i][j] + bi_[n];
            size_t oidx = (((size_t)(b * H_CNT + h) * S_LEN) + s) * D_HD + d;
            yr[oidx] = __float2bfloat16(vr);
            yi[oidx] = __float2bfloat16(vi);
        }
    }
}

// ---------------------------------------------------------------------------
// Kernel 2: complex attention with split softmax (flash-style, online).
//   Q,K,V: bf16 [B*H, S, D].  Output AO: fp32 [B, S, E] (e = h*64+d).
// grid (S/64, B*H), block 256.  Thread (r = tid>>2, part = tid&3) owns
// q-row r of the tile and the 16-wide column slice part*16..+15 (for both
// the score columns and the output d-columns).
// ---------------------------------------------------------------------------
__global__ __launch_bounds__(256) void cattn(
    const __hip_bfloat16* __restrict__ Qr, const __hip_bfloat16* __restrict__ Qi,
    const __hip_bfloat16* __restrict__ Kr, const __hip_bfloat16* __restrict__ Ki,
    const __hip_bfloat16* __restrict__ Vr, const __hip_bfloat16* __restrict__ Vi,
    float* __restrict__ AOr, float* __restrict__ AOi)
{
    __shared__ float qr_s[64][65], qi_s[64][65];
    __shared__ float kr_s[64][65], ki_s[64][65];
    __shared__ float vr_s[64][65], vi_s[64][65];
    __shared__ float pr_s[64][65], pi_s[64][65];

    const int bh = blockIdx.y;           // b*H + h
    const int b  = bh >> 4, h = bh & 15;
    const int q0 = blockIdx.x * 64;
    const int tid = threadIdx.x;
    const int r    = tid >> 2;           // q row in tile
    const int part = tid & 3;
    const int d0   = part * 16;

    const size_t qbase = ((size_t)bh * S_LEN + q0) * D_HD;
    for (int e = tid; e < 64 * 64; e += 256) {
        int rr = e >> 6, c = e & 63;
        qr_s[rr][c] = __bfloat162float(Qr[qbase + e]);
        qi_s[rr][c] = __bfloat162float(Qi[qbase + e]);
    }

    float m_r = -1e30f, l_r = 0.f, m_i = -1e30f, l_i = 0.f;
    float accAr[16] = {}, accAi[16] = {}, accBr[16] = {}, accBi[16] = {};

    for (int kt = 0; kt < 16; ++kt) {
        __syncthreads();   // previous iteration done reading K/V/P tiles
        const size_t kbase = ((size_t)bh * S_LEN + kt * 64) * D_HD;
        for (int e = tid; e < 64 * 64; e += 256) {
            int rr = e >> 6, c = e & 63;
            kr_s[rr][c] = __bfloat162float(Kr[kbase + e]);
            ki_s[rr][c] = __bfloat162float(Ki[kbase + e]);
            vr_s[rr][c] = __bfloat162float(Vr[kbase + e]);
            vi_s[rr][c] = __bfloat162float(Vi[kbase + e]);
        }
        __syncthreads();

        // --- scores for my 16 columns ---
        float sr[16], si[16];
#pragma unroll
        for (int j = 0; j < 16; ++j) { sr[j] = 0.f; si[j] = 0.f; }
        for (int d = 0; d < 64; ++d) {
            float qr = qr_s[r][d], qi = qi_s[r][d];
#pragma unroll
            for (int j = 0; j < 16; ++j) {
                float kr = kr_s[d0 + j][d], ki = ki_s[d0 + j][d];
                sr[j] += qr * kr - qi * ki;
                si[j] += qr * ki + qi * kr;
            }
        }

        // --- online softmax update (real and imag independently) ---
        float tmax_r = -1e30f, tmax_i = -1e30f;
#pragma unroll
        for (int j = 0; j < 16; ++j) {
            sr[j] *= 0.125f; si[j] *= 0.125f;
            tmax_r = fmaxf(tmax_r, sr[j]);
            tmax_i = fmaxf(tmax_i, si[j]);
        }
        tmax_r = fmaxf(tmax_r, __shfl_xor(tmax_r, 1));
        tmax_r = fmaxf(tmax_r, __shfl_xor(tmax_r, 2));
        tmax_i = fmaxf(tmax_i, __shfl_xor(tmax_i, 1));
        tmax_i = fmaxf(tmax_i, __shfl_xor(tmax_i, 2));
        float mnew_r = fmaxf(m_r, tmax_r);
        float mnew_i = fmaxf(m_i, tmax_i);
        float fr = __expf(m_r - mnew_r);
        float fi = __expf(m_i - mnew_i);
        float sum_r = 0.f, sum_i = 0.f;
#pragma unroll
        for (int j = 0; j < 16; ++j) {
            float pr = __expf(sr[j] - mnew_r);
            float pi = __expf(si[j] - mnew_i);
            pr_s[r][d0 + j] = pr;
            pi_s[r][d0 + j] = pi;
            sum_r += pr; sum_i += pi;
        }
        sum_r += __shfl_xor(sum_r, 1); sum_r += __shfl_xor(sum_r, 2);
        sum_i += __shfl_xor(sum_i, 1); sum_i += __shfl_xor(sum_i, 2);
        l_r = l_r * fr + sum_r;
        l_i = l_i * fi + sum_i;
        m_r = mnew_r; m_i = mnew_i;
#pragma unroll
        for (int j = 0; j < 16; ++j) {
            accAr[j] *= fr; accAi[j] *= fr;
            accBr[j] *= fi; accBi[j] *= fi;
        }
        __syncthreads();   // P tiles fully written (safety; same-wave anyway)

        // --- PV: accumulate Pr@Vr, Pr@Vi, Pi@Vr, Pi@Vi ---
        for (int k = 0; k < 64; ++k) {
            float pr = pr_s[r][k], pi = pi_s[r][k];
#pragma unroll
            for (int j = 0; j < 16; ++j) {
                float vr = vr_s[k][d0 + j], vi = vi_s[k][d0 + j];
                accAr[j] += pr * vr;
                accAi[j] += pr * vi;
                accBr[j] += pi * vr;
                accBi[j] += pi * vi;
            }
        }
    }

    const float inv_lr = 1.f / l_r, inv_li = 1.f / l_i;
    const size_t obase = ((size_t)b * S_LEN + (q0 + r)) * E_SZ + h * 64;
#pragma unroll
    for (int j = 0; j < 16; ++j) {
        AOr[obase + d0 + j] = accAr[j] * inv_lr - accBi[j] * inv_li;
        AOi[obase + d0 + j] = accAi[j] * inv_lr + accBr[j] * inv_li;
    }
}

// ---------------------------------------------------------------------------
// Kernel 3: output projection.  x: fp32 [B,S,E] (row m = b*S + s).
// out: fp32 [S,B,E,2]  (real=last-dim 0, imag=1)
// ---------------------------------------------------------------------------
__global__ __launch_bounds__(256) void cproj_o(
    const float* __restrict__ xr, const float* __restrict__ xi,
    const float* __restrict__ wr_, const float* __restrict__ wi_,
    const float* __restrict__ br_, const float* __restrict__ bi_,
    float* __restrict__ out)
{
    __shared__ float sxr[64][17], sxi[64][17], swr[64][17], swi[64][17];
    const int n0 = blockIdx.x * 64;
    const int m0 = blockIdx.y * 64;
    const int tid = threadIdx.x;
    const int tx = tid & 15, ty = tid >> 4;
    const int lrow = tid >> 4, lcol = tid & 15;

    float accr[4][4] = {}, acci[4][4] = {};

    for (int k0 = 0; k0 < E_SZ; k0 += 16) {
#pragma unroll
        for (int i = 0; i < 4; ++i) {
            int r = lrow + 16 * i;
            sxr[r][lcol] = xr[(size_t)(m0 + r) * E_SZ + k0 + lcol];
            sxi[r][lcol] = xi[(size_t)(m0 + r) * E_SZ + k0 + lcol];
            swr[r][lcol] = wr_[(size_t)(n0 + r) * E_SZ + k0 + lcol];
            swi[r][lcol] = wi_[(size_t)(n0 + r) * E_SZ + k0 + lcol];
        }
        __syncthreads();
#pragma unroll
        for (int kk = 0; kk < 16; ++kk) {
            float ar[4], ai[4], brg[4], big[4];
#pragma unroll
            for (int i = 0; i < 4; ++i) {
                ar[i]  = sxr[ty + 16 * i][kk];
                ai[i]  = sxi[ty + 16 * i][kk];
                brg[i] = swr[tx + 16 * i][kk];
                big[i] = swi[tx + 16 * i][kk];
            }
#pragma unroll
            for (int i = 0; i < 4; ++i)
#pragma unroll
                for (int j = 0; j < 4; ++j) {
                    accr[i][j] += ar[i] * brg[j] - ai[i] * big[j];
                    acci[i][j] += ar[i] * big[j] + ai[i] * brg[j];
                }
        }
        __syncthreads();
    }
#pragma unroll
    for (int i = 0; i < 4; ++i) {
        int m = m0 + ty + 16 * i;
        int b = m >> 10;   // m = b*S + s
        int s = m & 1023;
#pragma unroll
        for (int j = 0; j < 4; ++j) {
            int n = n0 + tx + 16 * j;
            float vr = accr[i][j] + br_[n];
            float vi = acci[i][j] + bi_[n];
            size_t oidx = (((size_t)(s * B_SZ + b) * E_SZ) + n) * 2;
            out[oidx + 0] = vr;
            out[oidx + 1] = vi;
        }
    }
}

extern "C" void kernel_launch(void* const* d_in, const int* in_sizes, int n_in,
                              void* d_out, int out_size, void* d_ws, size_t ws_size,
                              hipStream_t stream)
{
    const float* query_r = (const float*)d_in[0];
    const float* query_i = (const float*)d_in[1];
    const float* key_r   = (const float*)d_in[2];
    const float* key_i   = (const float*)d_in[3];
    const float* value_r = (const float*)d_in[4];
    const float* value_i = (const float*)d_in[5];
    const float* wq_r = (const float*)d_in[6];
    const float* wq_i = (const float*)d_in[7];
    const float* bq_r = (const float*)d_in[8];
    const float* bq_i = (const float*)d_in[9];
    const float* wk_r = (const float*)d_in[10];
    const float* wk_i = (const float*)d_in[11];
    const float* bk_r = (const float*)d_in[12];
    const float* bk_i = (const float*)d_in[13];
    const float* wv_r = (const float*)d_in[14];
    const float* wv_i = (const float*)d_in[15];
    const float* bv_r = (const float*)d_in[16];
    const float* bv_i = (const float*)d_in[17];
    const float* wo_r = (const float*)d_in[18];
    const float* wo_i = (const float*)d_in[19];
    const float* bo_r = (const float*)d_in[20];
    const float* bo_i = (const float*)d_in[21];

    // workspace layout: 6 bf16 [B*H,S,D] buffers then 2 fp32 [B,S,E] buffers
    __hip_bfloat16* Qr = (__hip_bfloat16*)d_ws;
    __hip_bfloat16* Qi = Qr + (size_t)N1;
    __hip_bfloat16* Kr = Qi + (size_t)N1;
    __hip_bfloat16* Ki = Kr + (size_t)N1;
    __hip_bfloat16* Vr = Ki + (size_t)N1;
    __hip_bfloat16* Vi = Vr + (size_t)N1;
    float* AOr = (float*)(Vi + (size_t)N1);
    float* AOi = AOr + (size_t)N1;

    dim3 blk(256);
    dim3 gproj(E_SZ / 64, (S_LEN * B_SZ) / 64);
    cproj_qkv<<<gproj, blk, 0, stream>>>(query_r, query_i, wq_r, wq_i, bq_r, bq_i, Qr, Qi);
    cproj_qkv<<<gproj, blk, 0, stream>>>(key_r,   key_i,   wk_r, wk_i, bk_r, bk_i, Kr, Ki);
    cproj_qkv<<<gproj, blk, 0, stream>>>(value_r, value_i, wv_r, wv_i, bv_r, bv_i, Vr, Vi);

    dim3 gattn(S_LEN / 64, B_SZ * H_CNT);
    cattn<<<gattn, blk, 0, stream>>>(Qr, Qi, Kr, Ki, Vr, Vi, AOr, AOi);

    cproj_o<<<gproj, blk, 0, stream>>>(AOr, AOi, wo_r, wo_i, bo_r, bo_i, (float*)d_out);
}

// Round 2
// 2377.098 us; speedup vs baseline: 3.5150x; 3.5150x over previous
//
#include <hip/hip_runtime.h>
#include <hip/hip_bf16.h>
#include <stdint.h>

#define S_LEN 1024
#define B_SZ  4
#define E_SZ  1024
#define H_CNT 16
#define D_HD  64
#define N1    (B_SZ * H_CNT * S_LEN * D_HD)   // 4194304 elements per component
#define WELEM (E_SZ * E_SZ)                   // 1048576

typedef __attribute__((ext_vector_type(8))) short short8;
typedef __attribute__((ext_vector_type(4))) float f32x4;

__device__ __forceinline__ ushort f2bf(float f) {
  union { float f; uint32_t u; } v; v.f = f;
  uint32_t u = v.u;
  uint32_t r = (u + 0x7fffu + ((u >> 16) & 1u)) >> 16;  // RNE
  return (ushort)r;
}
__device__ __forceinline__ float bf2f(ushort u) {
  union { uint32_t u; float f; } v; v.u = ((uint32_t)u) << 16;
  return v.f;
}
__device__ __forceinline__ short8 pack8(float4 a, float4 b) {
  short8 r;
  r[0] = (short)f2bf(a.x); r[1] = (short)f2bf(a.y);
  r[2] = (short)f2bf(a.z); r[3] = (short)f2bf(a.w);
  r[4] = (short)f2bf(b.x); r[5] = (short)f2bf(b.y);
  r[6] = (short)f2bf(b.z); r[7] = (short)f2bf(b.w);
  return r;
}
static __device__ __forceinline__ f32x4 mfma16(short8 a, short8 b, f32x4 c) {
  return __builtin_amdgcn_mfma_f32_16x16x32_bf16(a, b, c, 0, 0, 0);
}

// ---------------------------------------------------------------------------
// Cast 8 fp32 weight matrices [E,E] to bf16, concatenated into dst.
// grid 8192 x 256; each thread converts 4 elements.
// ---------------------------------------------------------------------------
__global__ __launch_bounds__(256) void cast_w8(
    const float* __restrict__ s0, const float* __restrict__ s1,
    const float* __restrict__ s2, const float* __restrict__ s3,
    const float* __restrict__ s4, const float* __restrict__ s5,
    const float* __restrict__ s6, const float* __restrict__ s7,
    ushort* __restrict__ dst)
{
  const size_t i = (size_t)blockIdx.x * blockDim.x + threadIdx.x;
  const size_t e = i * 4;                     // element index (total 8*WELEM)
  const int which = (int)(e >> 20);           // WELEM = 2^20
  const size_t off = e & (WELEM - 1);
  const float* s = which < 4
      ? (which < 2 ? (which == 0 ? s0 : s1) : (which == 2 ? s2 : s3))
      : (which < 6 ? (which == 4 ? s4 : s5) : (which == 6 ? s6 : s7));
  const float4 f = *(const float4*)(s + off);
  ushort4 u;
  u.x = f2bf(f.x); u.y = f2bf(f.y); u.z = f2bf(f.z); u.w = f2bf(f.w);
  *(ushort4*)(dst + e) = u;
}

// ---------------------------------------------------------------------------
// Complex bf16 MFMA GEMM, QKV flavor.
//   A = x (fp32, [4096,1024] row-major, row m = s*B+b), cast to bf16 in-flight
//   B = W (bf16, [1024,1024] row-major [out,in])   y = x @ W^T + bias
// Block tile 128x128, BK=32, 256 threads = 4 waves (2x2), wave tile 64x64.
// Output scattered bf16 into [B,H,S,D].
// ---------------------------------------------------------------------------
__global__ __launch_bounds__(256) void cgemm_qkv(
    const float* __restrict__ xr, const float* __restrict__ xi,
    const ushort* __restrict__ wre, const ushort* __restrict__ wim,
    const float* __restrict__ bre, const float* __restrict__ bim,
    ushort* __restrict__ yr, ushort* __restrict__ yi)
{
  __shared__ ushort sAr[128][32], sAi[128][32], sBr[128][32], sBi[128][32];
  const int tid  = threadIdx.x;
  const int lane = tid & 63;
  const int wid  = tid >> 6;
  const int wrow = wid >> 1, wcol = wid & 1;
  const int fr = lane & 15, fq = lane >> 4;
  const int m0 = blockIdx.y * 128, n0 = blockIdx.x * 128;
  const int srow = tid >> 1;
  const int scol = (tid & 1) * 16;

  f32x4 accR[4][4] = {}, accI[4][4] = {};

  for (int kt = 0; kt < E_SZ / 32; ++kt) {
    const int k0 = kt * 32;
    // global -> regs (before barrier: overlaps previous MFMA phase)
    const float4* par = (const float4*)&xr[(size_t)(m0 + srow) * E_SZ + k0 + scol];
    const float4* pai = (const float4*)&xi[(size_t)(m0 + srow) * E_SZ + k0 + scol];
    float4 fr0 = par[0], fr1 = par[1], fr2 = par[2], fr3 = par[3];
    float4 fi0 = pai[0], fi1 = pai[1], fi2 = pai[2], fi3 = pai[3];
    const short8* pbr = (const short8*)&wre[(size_t)(n0 + srow) * E_SZ + k0 + scol];
    const short8* pbi = (const short8*)&wim[(size_t)(n0 + srow) * E_SZ + k0 + scol];
    short8 wbr0 = pbr[0], wbr1 = pbr[1];
    short8 wbi0 = pbi[0], wbi1 = pbi[1];
    short8 war0 = pack8(fr0, fr1), war1 = pack8(fr2, fr3);
    short8 wai0 = pack8(fi0, fi1), wai1 = pack8(fi2, fi3);

    __syncthreads();   // all reads of previous tile done
    *(short8*)&sAr[srow][scol]     = war0;
    *(short8*)&sAr[srow][scol + 8] = war1;
    *(short8*)&sAi[srow][scol]     = wai0;
    *(short8*)&sAi[srow][scol + 8] = wai1;
    *(short8*)&sBr[srow][scol]     = wbr0;
    *(short8*)&sBr[srow][scol + 8] = wbr1;
    *(short8*)&sBi[srow][scol]     = wbi0;
    *(short8*)&sBi[srow][scol + 8] = wbi1;
    __syncthreads();   // tile ready

    short8 a_r[4], a_i[4], a_n[4], b_r[4], b_i[4];
#pragma unroll
    for (int mi = 0; mi < 4; ++mi) {
      a_r[mi] = *(const short8*)&sAr[wrow * 64 + mi * 16 + fr][fq * 8];
      a_i[mi] = *(const short8*)&sAi[wrow * 64 + mi * 16 + fr][fq * 8];
      a_n[mi] = a_i[mi] ^ (short)0x8000;   // -Ai
    }
#pragma unroll
    for (int ni = 0; ni < 4; ++ni) {
      b_r[ni] = *(const short8*)&sBr[wcol * 64 + ni * 16 + fr][fq * 8];
      b_i[ni] = *(const short8*)&sBi[wcol * 64 + ni * 16 + fr][fq * 8];
    }
#pragma unroll
    for (int mi = 0; mi < 4; ++mi)
#pragma unroll
      for (int ni = 0; ni < 4; ++ni) {
        accR[mi][ni] = mfma16(a_r[mi], b_r[ni], accR[mi][ni]);  // +Ar*Br
        accR[mi][ni] = mfma16(a_n[mi], b_i[ni], accR[mi][ni]);  // -Ai*Bi
        accI[mi][ni] = mfma16(a_r[mi], b_i[ni], accI[mi][ni]);  // +Ar*Bi
        accI[mi][ni] = mfma16(a_i[mi], b_r[ni], accI[mi][ni]);  // +Ai*Br
      }
  }

  // epilogue: C/D layout col=lane&15, row=(lane>>4)*4+reg
#pragma unroll
  for (int ni = 0; ni < 4; ++ni) {
    const int n = n0 + wcol * 64 + ni * 16 + fr;
    const float bR = bre[n], bI = bim[n];
    const int h = n >> 6, d = n & 63;
#pragma unroll
    for (int mi = 0; mi < 4; ++mi) {
      const int mb = m0 + wrow * 64 + mi * 16 + fq * 4;
#pragma unroll
      for (int q = 0; q < 4; ++q) {
        const int m = mb + q;
        const int s = m >> 2, b = m & 3;      // m = s*B + b
        const size_t o = (((size_t)(b * H_CNT + h) * S_LEN) + s) * D_HD + d;
        yr[o] = f2bf(accR[mi][ni][q] + bR);
        yi[o] = f2bf(accI[mi][ni][q] + bI);
      }
    }
  }
}

// ---------------------------------------------------------------------------
// Complex bf16 MFMA GEMM, output-projection flavor.
//   A = AO (bf16, [B,S,E] row-major, row m = b*S+s), B = Wo (bf16)
//   out fp32 [S,B,E,2] interleaved (real, imag), + bias.
// ---------------------------------------------------------------------------
__global__ __launch_bounds__(256) void cgemm_o(
    const ushort* __restrict__ aor, const ushort* __restrict__ aoi,
    const ushort* __restrict__ wre, const ushort* __restrict__ wim,
    const float* __restrict__ bre, const float* __restrict__ bim,
    float* __restrict__ out)
{
  __shared__ ushort sAr[128][32], sAi[128][32], sBr[128][32], sBi[128][32];
  const int tid  = threadIdx.x;
  const int lane = tid & 63;
  const int wid  = tid >> 6;
  const int wrow = wid >> 1, wcol = wid & 1;
  const int fr = lane & 15, fq = lane >> 4;
  const int m0 = blockIdx.y * 128, n0 = blockIdx.x * 128;
  const int srow = tid >> 1;
  const int scol = (tid & 1) * 16;

  f32x4 accR[4][4] = {}, accI[4][4] = {};

  for (int kt = 0; kt < E_SZ / 32; ++kt) {
    const int k0 = kt * 32;
    const short8* par = (const short8*)&aor[(size_t)(m0 + srow) * E_SZ + k0 + scol];
    const short8* pai = (const short8*)&aoi[(size_t)(m0 + srow) * E_SZ + k0 + scol];
    short8 war0 = par[0], war1 = par[1];
    short8 wai0 = pai[0], wai1 = pai[1];
    const short8* pbr = (const short8*)&wre[(size_t)(n0 + srow) * E_SZ + k0 + scol];
    const short8* pbi = (const short8*)&wim[(size_t)(n0 + srow) * E_SZ + k0 + scol];
    short8 wbr0 = pbr[0], wbr1 = pbr[1];
    short8 wbi0 = pbi[0], wbi1 = pbi[1];

    __syncthreads();
    *(short8*)&sAr[srow][scol]     = war0;
    *(short8*)&sAr[srow][scol + 8] = war1;
    *(short8*)&sAi[srow][scol]     = wai0;
    *(short8*)&sAi[srow][scol + 8] = wai1;
    *(short8*)&sBr[srow][scol]     = wbr0;
    *(short8*)&sBr[srow][scol + 8] = wbr1;
    *(short8*)&sBi[srow][scol]     = wbi0;
    *(short8*)&sBi[srow][scol + 8] = wbi1;
    __syncthreads();

    short8 a_r[4], a_i[4], a_n[4], b_r[4], b_i[4];
#pragma unroll
    for (int mi = 0; mi < 4; ++mi) {
      a_r[mi] = *(const short8*)&sAr[wrow * 64 + mi * 16 + fr][fq * 8];
      a_i[mi] = *(const short8*)&sAi[wrow * 64 + mi * 16 + fr][fq * 8];
      a_n[mi] = a_i[mi] ^ (short)0x8000;
    }
#pragma unroll
    for (int ni = 0; ni < 4; ++ni) {
      b_r[ni] = *(const short8*)&sBr[wcol * 64 + ni * 16 + fr][fq * 8];
      b_i[ni] = *(const short8*)&sBi[wcol * 64 + ni * 16 + fr][fq * 8];
    }
#pragma unroll
    for (int mi = 0; mi < 4; ++mi)
#pragma unroll
      for (int ni = 0; ni < 4; ++ni) {
        accR[mi][ni] = mfma16(a_r[mi], b_r[ni], accR[mi][ni]);
        accR[mi][ni] = mfma16(a_n[mi], b_i[ni], accR[mi][ni]);
        accI[mi][ni] = mfma16(a_r[mi], b_i[ni], accI[mi][ni]);
        accI[mi][ni] = mfma16(a_i[mi], b_r[ni], accI[mi][ni]);
      }
  }

#pragma unroll
  for (int ni = 0; ni < 4; ++ni) {
    const int n = n0 + wcol * 64 + ni * 16 + fr;
    const float bR = bre[n], bI = bim[n];
#pragma unroll
    for (int mi = 0; mi < 4; ++mi) {
      const int mb = m0 + wrow * 64 + mi * 16 + fq * 4;
#pragma unroll
      for (int q = 0; q < 4; ++q) {
        const int m = mb + q;
        const int b = m >> 10, s = m & 1023;  // m = b*S + s
        const size_t o = (((size_t)(s * B_SZ + b) * E_SZ) + n) * 2;
        out[o]     = accR[mi][ni][q] + bR;
        out[o + 1] = accI[mi][ni][q] + bI;
      }
    }
  }
}

// ---------------------------------------------------------------------------
// Complex attention with split softmax (unchanged structure; bf16 AO output).
// ---------------------------------------------------------------------------
__global__ __launch_bounds__(256) void cattn(
    const ushort* __restrict__ Qr, const ushort* __restrict__ Qi,
    const ushort* __restrict__ Kr, const ushort* __restrict__ Ki,
    const ushort* __restrict__ Vr, const ushort* __restrict__ Vi,
    ushort* __restrict__ AOr, ushort* __restrict__ AOi)
{
    __shared__ float qr_s[64][65], qi_s[64][65];
    __shared__ float kr_s[64][65], ki_s[64][65];
    __shared__ float vr_s[64][65], vi_s[64][65];
    __shared__ float pr_s[64][65], pi_s[64][65];

    const int bh = blockIdx.y;           // b*H + h
    const int b  = bh >> 4, h = bh & 15;
    const int q0 = blockIdx.x * 64;
    const int tid = threadIdx.x;
    const int r    = tid >> 2;
    const int part = tid & 3;
    const int d0   = part * 16;

    const size_t qbase = ((size_t)bh * S_LEN + q0) * D_HD;
    for (int e = tid; e < 64 * 64; e += 256) {
        int rr = e >> 6, c = e & 63;
        qr_s[rr][c] = bf2f(Qr[qbase + e]);
        qi_s[rr][c] = bf2f(Qi[qbase + e]);
    }

    float m_r = -1e30f, l_r = 0.f, m_i = -1e30f, l_i = 0.f;
    float accAr[16] = {}, accAi[16] = {}, accBr[16] = {}, accBi[16] = {};

    for (int kt = 0; kt < 16; ++kt) {
        __syncthreads();
        const size_t kbase = ((size_t)bh * S_LEN + kt * 64) * D_HD;
        for (int e = tid; e < 64 * 64; e += 256) {
            int rr = e >> 6, c = e & 63;
            kr_s[rr][c] = bf2f(Kr[kbase + e]);
            ki_s[rr][c] = bf2f(Ki[kbase + e]);
            vr_s[rr][c] = bf2f(Vr[kbase + e]);
            vi_s[rr][c] = bf2f(Vi[kbase + e]);
        }
        __syncthreads();

        float sr[16], si[16];
#pragma unroll
        for (int j = 0; j < 16; ++j) { sr[j] = 0.f; si[j] = 0.f; }
        for (int d = 0; d < 64; ++d) {
            float qr = qr_s[r][d], qi = qi_s[r][d];
#pragma unroll
            for (int j = 0; j < 16; ++j) {
                float kr = kr_s[d0 + j][d], ki = ki_s[d0 + j][d];
                sr[j] += qr * kr - qi * ki;
                si[j] += qr * ki + qi * kr;
            }
        }

        float tmax_r = -1e30f, tmax_i = -1e30f;
#pragma unroll
        for (int j = 0; j < 16; ++j) {
            sr[j] *= 0.125f; si[j] *= 0.125f;
            tmax_r = fmaxf(tmax_r, sr[j]);
            tmax_i = fmaxf(tmax_i, si[j]);
        }
        tmax_r = fmaxf(tmax_r, __shfl_xor(tmax_r, 1));
        tmax_r = fmaxf(tmax_r, __shfl_xor(tmax_r, 2));
        tmax_i = fmaxf(tmax_i, __shfl_xor(tmax_i, 1));
        tmax_i = fmaxf(tmax_i, __shfl_xor(tmax_i, 2));
        float mnew_r = fmaxf(m_r, tmax_r);
        float mnew_i = fmaxf(m_i, tmax_i);
        float fr = __expf(m_r - mnew_r);
        float fi = __expf(m_i - mnew_i);
        float sum_r = 0.f, sum_i = 0.f;
#pragma unroll
        for (int j = 0; j < 16; ++j) {
            float pr = __expf(sr[j] - mnew_r);
            float pi = __expf(si[j] - mnew_i);
            pr_s[r][d0 + j] = pr;
            pi_s[r][d0 + j] = pi;
            sum_r += pr; sum_i += pi;
        }
        sum_r += __shfl_xor(sum_r, 1); sum_r += __shfl_xor(sum_r, 2);
        sum_i += __shfl_xor(sum_i, 1); sum_i += __shfl_xor(sum_i, 2);
        l_r = l_r * fr + sum_r;
        l_i = l_i * fi + sum_i;
        m_r = mnew_r; m_i = mnew_i;
#pragma unroll
        for (int j = 0; j < 16; ++j) {
            accAr[j] *= fr; accAi[j] *= fr;
            accBr[j] *= fi; accBi[j] *= fi;
        }
        __syncthreads();

        for (int k = 0; k < 64; ++k) {
            float pr = pr_s[r][k], pi = pi_s[r][k];
#pragma unroll
            for (int j = 0; j < 16; ++j) {
                float vr = vr_s[k][d0 + j], vi = vi_s[k][d0 + j];
                accAr[j] += pr * vr;
                accAi[j] += pr * vi;
                accBr[j] += pi * vr;
                accBi[j] += pi * vi;
            }
        }
    }

    const float inv_lr = 1.f / l_r, inv_li = 1.f / l_i;
    const size_t obase = ((size_t)b * S_LEN + (q0 + r)) * E_SZ + h * 64;
#pragma unroll
    for (int j = 0; j < 16; ++j) {
        AOr[obase + d0 + j] = f2bf(accAr[j] * inv_lr - accBi[j] * inv_li);
        AOi[obase + d0 + j] = f2bf(accAi[j] * inv_lr + accBr[j] * inv_li);
    }
}

extern "C" void kernel_launch(void* const* d_in, const int* in_sizes, int n_in,
                              void* d_out, int out_size, void* d_ws, size_t ws_size,
                              hipStream_t stream)
{
    const float* query_r = (const float*)d_in[0];
    const float* query_i = (const float*)d_in[1];
    const float* key_r   = (const float*)d_in[2];
    const float* key_i   = (const float*)d_in[3];
    const float* value_r = (const float*)d_in[4];
    const float* value_i = (const float*)d_in[5];
    const float* wq_r = (const float*)d_in[6];
    const float* wq_i = (const float*)d_in[7];
    const float* bq_r = (const float*)d_in[8];
    const float* bq_i = (const float*)d_in[9];
    const float* wk_r = (const float*)d_in[10];
    const float* wk_i = (const float*)d_in[11];
    const float* bk_r = (const float*)d_in[12];
    const float* bk_i = (const float*)d_in[13];
    const float* wv_r = (const float*)d_in[14];
    const float* wv_i = (const float*)d_in[15];
    const float* bv_r = (const float*)d_in[16];
    const float* bv_i = (const float*)d_in[17];
    const float* wo_r = (const float*)d_in[18];
    const float* wo_i = (const float*)d_in[19];
    const float* bo_r = (const float*)d_in[20];
    const float* bo_i = (const float*)d_in[21];

    // workspace (all bf16/ushort): 6*N1 QKV | 8*WELEM weights | 2*N1 AO = 80 MiB
    ushort* ws   = (ushort*)d_ws;
    ushort* Qr   = ws;
    ushort* Qi   = Qr + (size_t)N1;
    ushort* Kr   = Qi + (size_t)N1;
    ushort* Ki   = Kr + (size_t)N1;
    ushort* Vr   = Ki + (size_t)N1;
    ushort* Vi   = Vr + (size_t)N1;
    ushort* Wb   = Vi + (size_t)N1;
    ushort* Wq_r = Wb + 0 * (size_t)WELEM;
    ushort* Wq_i = Wb + 1 * (size_t)WELEM;
    ushort* Wk_r = Wb + 2 * (size_t)WELEM;
    ushort* Wk_i = Wb + 3 * (size_t)WELEM;
    ushort* Wv_r = Wb + 4 * (size_t)WELEM;
    ushort* Wv_i = Wb + 5 * (size_t)WELEM;
    ushort* Wo_r = Wb + 6 * (size_t)WELEM;
    ushort* Wo_i = Wb + 7 * (size_t)WELEM;
    ushort* AOr  = Wb + 8 * (size_t)WELEM;
    ushort* AOi  = AOr + (size_t)N1;

    cast_w8<<<8192, 256, 0, stream>>>(wq_r, wq_i, wk_r, wk_i,
                                      wv_r, wv_i, wo_r, wo_i, Wb);

    dim3 gg(E_SZ / 128, (S_LEN * B_SZ) / 128);   // (8, 32)
    cgemm_qkv<<<gg, 256, 0, stream>>>(query_r, query_i, Wq_r, Wq_i, bq_r, bq_i, Qr, Qi);
    cgemm_qkv<<<gg, 256, 0, stream>>>(key_r,   key_i,   Wk_r, Wk_i, bk_r, bk_i, Kr, Ki);
    cgemm_qkv<<<gg, 256, 0, stream>>>(value_r, value_i, Wv_r, Wv_i, bv_r, bv_i, Vr, Vi);

    cattn<<<dim3(S_LEN / 64, B_SZ * H_CNT), 256, 0, stream>>>(
        Qr, Qi, Kr, Ki, Vr, Vi, AOr, AOi);

    cgemm_o<<<gg, 256, 0, stream>>>(AOr, AOi, Wo_r, Wo_i, bo_r, bo_i, (float*)d_out);
}

// Round 3
// 503.439 us; speedup vs baseline: 16.5969x; 4.7217x over previous
//
#include <hip/hip_runtime.h>
#include <hip/hip_bf16.h>
#include <stdint.h>

#define S_LEN 1024
#define B_SZ  4
#define E_SZ  1024
#define H_CNT 16
#define D_HD  64
#define N1    (B_SZ * H_CNT * S_LEN * D_HD)   // 4194304 elements per component
#define WELEM (E_SZ * E_SZ)                   // 1048576

typedef __attribute__((ext_vector_type(8))) short short8;
typedef __attribute__((ext_vector_type(4))) float f32x4;

__device__ __forceinline__ ushort f2bf(float f) {
  union { float f; uint32_t u; } v; v.f = f;
  uint32_t u = v.u;
  uint32_t r = (u + 0x7fffu + ((u >> 16) & 1u)) >> 16;  // RNE
  return (ushort)r;
}
__device__ __forceinline__ float bf2f(ushort u) {
  union { uint32_t u; float f; } v; v.u = ((uint32_t)u) << 16;
  return v.f;
}
__device__ __forceinline__ short8 pack8(float4 a, float4 b) {
  short8 r;
  r[0] = (short)f2bf(a.x); r[1] = (short)f2bf(a.y);
  r[2] = (short)f2bf(a.z); r[3] = (short)f2bf(a.w);
  r[4] = (short)f2bf(b.x); r[5] = (short)f2bf(b.y);
  r[6] = (short)f2bf(b.z); r[7] = (short)f2bf(b.w);
  return r;
}
static __device__ __forceinline__ f32x4 mfma16(short8 a, short8 b, f32x4 c) {
  return __builtin_amdgcn_mfma_f32_16x16x32_bf16(a, b, c, 0, 0, 0);
}

// ---------------------------------------------------------------------------
// Cast 8 fp32 weight matrices [E,E] to bf16, concatenated into dst.
// ---------------------------------------------------------------------------
__global__ __launch_bounds__(256) void cast_w8(
    const float* __restrict__ s0, const float* __restrict__ s1,
    const float* __restrict__ s2, const float* __restrict__ s3,
    const float* __restrict__ s4, const float* __restrict__ s5,
    const float* __restrict__ s6, const float* __restrict__ s7,
    ushort* __restrict__ dst)
{
  const size_t i = (size_t)blockIdx.x * blockDim.x + threadIdx.x;
  const size_t e = i * 4;
  const int which = (int)(e >> 20);
  const size_t off = e & (WELEM - 1);
  const float* s = which < 4
      ? (which < 2 ? (which == 0 ? s0 : s1) : (which == 2 ? s2 : s3))
      : (which < 6 ? (which == 4 ? s4 : s5) : (which == 6 ? s6 : s7));
  const float4 f = *(const float4*)(s + off);
  ushort4 u;
  u.x = f2bf(f.x); u.y = f2bf(f.y); u.z = f2bf(f.z); u.w = f2bf(f.w);
  *(ushort4*)(dst + e) = u;
}

// ---------------------------------------------------------------------------
// Complex bf16 MFMA GEMM for input projections.
//   A = x (fp32, [4096,1024] row-major, row m = s*B+b), cast bf16 in-flight
//   B = W (bf16, [1024,1024] [out,in])    y = x @ W^T + bias
// VT=false: output [B,H,S,D] (Q,K).  VT=true: output [B,H,D,S] (V transposed).
// ---------------------------------------------------------------------------
template<bool VT>
__global__ __launch_bounds__(256) void cgemm_in(
    const float* __restrict__ xr, const float* __restrict__ xi,
    const ushort* __restrict__ wre, const ushort* __restrict__ wim,
    const float* __restrict__ bre, const float* __restrict__ bim,
    ushort* __restrict__ yr, ushort* __restrict__ yi)
{
  __shared__ __align__(16) ushort sAr[128][32], sAi[128][32], sBr[128][32], sBi[128][32];
  const int tid  = threadIdx.x;
  const int lane = tid & 63;
  const int wid  = tid >> 6;
  const int wrow = wid >> 1, wcol = wid & 1;
  const int fr = lane & 15, fq = lane >> 4;
  const int m0 = blockIdx.y * 128, n0 = blockIdx.x * 128;
  const int srow = tid >> 1;
  const int scol = (tid & 1) * 16;

  f32x4 accR[4][4] = {}, accI[4][4] = {};

  for (int kt = 0; kt < E_SZ / 32; ++kt) {
    const int k0 = kt * 32;
    const float4* par = (const float4*)&xr[(size_t)(m0 + srow) * E_SZ + k0 + scol];
    const float4* pai = (const float4*)&xi[(size_t)(m0 + srow) * E_SZ + k0 + scol];
    float4 fr0 = par[0], fr1 = par[1], fr2 = par[2], fr3 = par[3];
    float4 fi0 = pai[0], fi1 = pai[1], fi2 = pai[2], fi3 = pai[3];
    const short8* pbr = (const short8*)&wre[(size_t)(n0 + srow) * E_SZ + k0 + scol];
    const short8* pbi = (const short8*)&wim[(size_t)(n0 + srow) * E_SZ + k0 + scol];
    short8 wbr0 = pbr[0], wbr1 = pbr[1];
    short8 wbi0 = pbi[0], wbi1 = pbi[1];
    short8 war0 = pack8(fr0, fr1), war1 = pack8(fr2, fr3);
    short8 wai0 = pack8(fi0, fi1), wai1 = pack8(fi2, fi3);

    __syncthreads();
    *(short8*)&sAr[srow][scol]     = war0;
    *(short8*)&sAr[srow][scol + 8] = war1;
    *(short8*)&sAi[srow][scol]     = wai0;
    *(short8*)&sAi[srow][scol + 8] = wai1;
    *(short8*)&sBr[srow][scol]     = wbr0;
    *(short8*)&sBr[srow][scol + 8] = wbr1;
    *(short8*)&sBi[srow][scol]     = wbi0;
    *(short8*)&sBi[srow][scol + 8] = wbi1;
    __syncthreads();

    short8 a_r[4], a_i[4], a_n[4], b_r[4], b_i[4];
#pragma unroll
    for (int mi = 0; mi < 4; ++mi) {
      a_r[mi] = *(const short8*)&sAr[wrow * 64 + mi * 16 + fr][fq * 8];
      a_i[mi] = *(const short8*)&sAi[wrow * 64 + mi * 16 + fr][fq * 8];
      a_n[mi] = a_i[mi] ^ (short)0x8000;
    }
#pragma unroll
    for (int ni = 0; ni < 4; ++ni) {
      b_r[ni] = *(const short8*)&sBr[wcol * 64 + ni * 16 + fr][fq * 8];
      b_i[ni] = *(const short8*)&sBi[wcol * 64 + ni * 16 + fr][fq * 8];
    }
#pragma unroll
    for (int mi = 0; mi < 4; ++mi)
#pragma unroll
      for (int ni = 0; ni < 4; ++ni) {
        accR[mi][ni] = mfma16(a_r[mi], b_r[ni], accR[mi][ni]);
        accR[mi][ni] = mfma16(a_n[mi], b_i[ni], accR[mi][ni]);
        accI[mi][ni] = mfma16(a_r[mi], b_i[ni], accI[mi][ni]);
        accI[mi][ni] = mfma16(a_i[mi], b_r[ni], accI[mi][ni]);
      }
  }

#pragma unroll
  for (int ni = 0; ni < 4; ++ni) {
    const int n = n0 + wcol * 64 + ni * 16 + fr;
    const float bR = bre[n], bI = bim[n];
    const int h = n >> 6, d = n & 63;
#pragma unroll
    for (int mi = 0; mi < 4; ++mi) {
      const int mb = m0 + wrow * 64 + mi * 16 + fq * 4;
#pragma unroll
      for (int q = 0; q < 4; ++q) {
        const int m = mb + q;
        const int s = m >> 2, b = m & 3;      // m = s*B + b
        size_t o;
        if (!VT) o = (((size_t)(b * H_CNT + h) * S_LEN) + s) * D_HD + d;
        else     o = (((size_t)(b * H_CNT + h) * D_HD) + d) * S_LEN + s;
        yr[o] = f2bf(accR[mi][ni][q] + bR);
        yi[o] = f2bf(accI[mi][ni][q] + bI);
      }
    }
  }
}

// ---------------------------------------------------------------------------
// Output projection: A = AO (bf16 [B,S,E], row m = b*S+s), out fp32 [S,B,E,2].
// ---------------------------------------------------------------------------
__global__ __launch_bounds__(256) void cgemm_o(
    const ushort* __restrict__ aor, const ushort* __restrict__ aoi,
    const ushort* __restrict__ wre, const ushort* __restrict__ wim,
    const float* __restrict__ bre, const float* __restrict__ bim,
    float* __restrict__ out)
{
  __shared__ __align__(16) ushort sAr[128][32], sAi[128][32], sBr[128][32], sBi[128][32];
  const int tid  = threadIdx.x;
  const int lane = tid & 63;
  const int wid  = tid >> 6;
  const int wrow = wid >> 1, wcol = wid & 1;
  const int fr = lane & 15, fq = lane >> 4;
  const int m0 = blockIdx.y * 128, n0 = blockIdx.x * 128;
  const int srow = tid >> 1;
  const int scol = (tid & 1) * 16;

  f32x4 accR[4][4] = {}, accI[4][4] = {};

  for (int kt = 0; kt < E_SZ / 32; ++kt) {
    const int k0 = kt * 32;
    const short8* par = (const short8*)&aor[(size_t)(m0 + srow) * E_SZ + k0 + scol];
    const short8* pai = (const short8*)&aoi[(size_t)(m0 + srow) * E_SZ + k0 + scol];
    short8 war0 = par[0], war1 = par[1];
    short8 wai0 = pai[0], wai1 = pai[1];
    const short8* pbr = (const short8*)&wre[(size_t)(n0 + srow) * E_SZ + k0 + scol];
    const short8* pbi = (const short8*)&wim[(size_t)(n0 + srow) * E_SZ + k0 + scol];
    short8 wbr0 = pbr[0], wbr1 = pbr[1];
    short8 wbi0 = pbi[0], wbi1 = pbi[1];

    __syncthreads();
    *(short8*)&sAr[srow][scol]     = war0;
    *(short8*)&sAr[srow][scol + 8] = war1;
    *(short8*)&sAi[srow][scol]     = wai0;
    *(short8*)&sAi[srow][scol + 8] = wai1;
    *(short8*)&sBr[srow][scol]     = wbr0;
    *(short8*)&sBr[srow][scol + 8] = wbr1;
    *(short8*)&sBi[srow][scol]     = wbi0;
    *(short8*)&sBi[srow][scol + 8] = wbi1;
    __syncthreads();

    short8 a_r[4], a_i[4], a_n[4], b_r[4], b_i[4];
#pragma unroll
    for (int mi = 0; mi < 4; ++mi) {
      a_r[mi] = *(const short8*)&sAr[wrow * 64 + mi * 16 + fr][fq * 8];
      a_i[mi] = *(const short8*)&sAi[wrow * 64 + mi * 16 + fr][fq * 8];
      a_n[mi] = a_i[mi] ^ (short)0x8000;
    }
#pragma unroll
    for (int ni = 0; ni < 4; ++ni) {
      b_r[ni] = *(const short8*)&sBr[wcol * 64 + ni * 16 + fr][fq * 8];
      b_i[ni] = *(const short8*)&sBi[wcol * 64 + ni * 16 + fr][fq * 8];
    }
#pragma unroll
    for (int mi = 0; mi < 4; ++mi)
#pragma unroll
      for (int ni = 0; ni < 4; ++ni) {
        accR[mi][ni] = mfma16(a_r[mi], b_r[ni], accR[mi][ni]);
        accR[mi][ni] = mfma16(a_n[mi], b_i[ni], accR[mi][ni]);
        accI[mi][ni] = mfma16(a_r[mi], b_i[ni], accI[mi][ni]);
        accI[mi][ni] = mfma16(a_i[mi], b_r[ni], accI[mi][ni]);
      }
  }

#pragma unroll
  for (int ni = 0; ni < 4; ++ni) {
    const int n = n0 + wcol * 64 + ni * 16 + fr;
    const float bR = bre[n], bI = bim[n];
#pragma unroll
    for (int mi = 0; mi < 4; ++mi) {
      const int mb = m0 + wrow * 64 + mi * 16 + fq * 4;
#pragma unroll
      for (int q = 0; q < 4; ++q) {
        const int m = mb + q;
        const int b = m >> 10, s = m & 1023;  // m = b*S + s
        const size_t o = (((size_t)(s * B_SZ + b) * E_SZ) + n) * 2;
        out[o]     = accR[mi][ni][q] + bR;
        out[o + 1] = accI[mi][ni][q] + bI;
      }
    }
  }
}

// ---------------------------------------------------------------------------
// MFMA complex flash attention with split softmax.
// grid (S/64, B*H), 256 threads = 4 waves; wave w owns q-rows [q0+16w, +16).
// Q,K: bf16 [BH,S,D]; Vt: bf16 [BH,D,S]; AO out: bf16 [B,S,E].
// LDS tiles XOR-swizzled: 16B chunk index ^= (row&7).
// ---------------------------------------------------------------------------
__global__ __launch_bounds__(256) void cattn_mfma(
    const ushort* __restrict__ Qr, const ushort* __restrict__ Qi,
    const ushort* __restrict__ Kr, const ushort* __restrict__ Ki,
    const ushort* __restrict__ Vtr, const ushort* __restrict__ Vti,
    ushort* __restrict__ AOr, ushort* __restrict__ AOi)
{
  __shared__ __align__(16) ushort sK[2][64][64];    // [comp][kc][d]
  __shared__ __align__(16) ushort sVt[2][64][64];   // [comp][d][k]
  __shared__ __align__(16) ushort sP[4][2][16][64]; // [wave][comp][q][k]

  const int tid  = threadIdx.x;
  const int lane = tid & 63;
  const int w    = tid >> 6;
  const int g    = lane >> 4;
  const int fr   = lane & 15;
  const int bh   = blockIdx.y;
  const int b    = bh >> 4, h = bh & 15;
  const int q0   = blockIdx.x * 64;

  // Q fragments (row = q0+16w+fr, contract slices kk*32 + g*8)
  const size_t qrow = (size_t)bh * S_LEN * D_HD + (size_t)(q0 + 16 * w + fr) * D_HD;
  short8 qfr[2], qfi[2], qfn[2];
#pragma unroll
  for (int kk = 0; kk < 2; ++kk) {
    qfr[kk] = *(const short8*)(Qr + qrow + kk * 32 + g * 8);
    qfi[kk] = *(const short8*)(Qi + qrow + kk * 32 + g * 8);
    qfn[kk] = qfi[kk] ^ (short)0x8000;
  }

  float m_r[4], l_r[4], m_i[4], l_i[4];
#pragma unroll
  for (int t = 0; t < 4; ++t) { m_r[t] = -1e30f; l_r[t] = 0.f; m_i[t] = -1e30f; l_i[t] = 0.f; }
  f32x4 accA[4] = {}, accAi[4] = {}, accB[4] = {}, accBi[4] = {};

  // staging: wave w owns one of {Kr,Ki,Vtr,Vti}
  const ushort* gsrc;
  ushort* dst;
  if      (w == 0) { gsrc = Kr  + (size_t)bh * S_LEN * D_HD; dst = &sK[0][0][0]; }
  else if (w == 1) { gsrc = Ki  + (size_t)bh * S_LEN * D_HD; dst = &sK[1][0][0]; }
  else if (w == 2) { gsrc = Vtr + (size_t)bh * D_HD * S_LEN; dst = &sVt[0][0][0]; }
  else             { gsrc = Vti + (size_t)bh * D_HD * S_LEN; dst = &sVt[1][0][0]; }
  const bool isK = (w < 2);

  ushort* pR = &sP[w][0][0][0];
  ushort* pI = &sP[w][1][0][0];

  for (int kt = 0; kt < 16; ++kt) {
    __syncthreads();   // prev tile fully consumed
#pragma unroll
    for (int it = 0; it < 8; ++it) {
      const int idx = it * 64 + lane;
      const int row = idx >> 3, c = idx & 7;
      const ushort* p = isK ? (gsrc + (size_t)kt * 4096 + (size_t)idx * 8)
                            : (gsrc + (size_t)row * S_LEN + kt * 64 + c * 8);
      short8 v = *(const short8*)p;
      *(short8*)((char*)dst + row * 128 + ((c ^ (row & 7)) << 4)) = v;
    }
    __syncthreads();   // tile ready

    // ---- QK^T ----
    f32x4 Sr[4], Si[4];
#pragma unroll
    for (int n = 0; n < 4; ++n) {
      f32x4 zr = {0.f, 0.f, 0.f, 0.f}, zi = {0.f, 0.f, 0.f, 0.f};
      const int kc = fr + 16 * n;
#pragma unroll
      for (int kk = 0; kk < 2; ++kk) {
        const int ch = kk * 4 + g;
        const int off = kc * 128 + ((ch ^ (kc & 7)) << 4);
        short8 krf = *(const short8*)((const char*)&sK[0][0][0] + off);
        short8 kif = *(const short8*)((const char*)&sK[1][0][0] + off);
        zr = mfma16(qfr[kk], krf, zr);
        zr = mfma16(qfn[kk], kif, zr);
        zi = mfma16(qfr[kk], kif, zi);
        zi = mfma16(qfi[kk], krf, zi);
      }
      Sr[n] = zr; Si[n] = zi;
    }
#pragma unroll
    for (int n = 0; n < 4; ++n) { Sr[n] *= 0.125f; Si[n] *= 0.125f; }

    // ---- online split softmax ----
    float tr[4], ti_[4];
#pragma unroll
    for (int t = 0; t < 4; ++t) {
      tr[t]  = fmaxf(fmaxf(Sr[0][t], Sr[1][t]), fmaxf(Sr[2][t], Sr[3][t]));
      ti_[t] = fmaxf(fmaxf(Si[0][t], Si[1][t]), fmaxf(Si[2][t], Si[3][t]));
    }
#pragma unroll
    for (int mm = 1; mm < 16; mm <<= 1)
#pragma unroll
      for (int t = 0; t < 4; ++t) {
        tr[t]  = fmaxf(tr[t],  __shfl_xor(tr[t],  mm));
        ti_[t] = fmaxf(ti_[t], __shfl_xor(ti_[t], mm));
      }
    float fR[4], fI[4], sumR[4], sumI[4];
#pragma unroll
    for (int t = 0; t < 4; ++t) {
      const float mnr = fmaxf(m_r[t], tr[t]);
      const float mni = fmaxf(m_i[t], ti_[t]);
      fR[t] = __expf(m_r[t] - mnr);
      fI[t] = __expf(m_i[t] - mni);
      m_r[t] = mnr; m_i[t] = mni;
      sumR[t] = 0.f; sumI[t] = 0.f;
    }
#pragma unroll
    for (int n = 0; n < 4; ++n) {
      const int k = fr + 16 * n;
      const int kch = k >> 3, klo = (k & 7) * 2;
#pragma unroll
      for (int t = 0; t < 4; ++t) {
        const int q = g * 4 + t;
        const float pr = __expf(Sr[n][t] - m_r[t]);
        const float pi = __expf(Si[n][t] - m_i[t]);
        sumR[t] += pr; sumI[t] += pi;
        const int off = q * 128 + ((kch ^ (q & 7)) << 4) + klo;
        *(ushort*)((char*)pR + off) = f2bf(pr);
        *(ushort*)((char*)pI + off) = f2bf(pi);
      }
    }
#pragma unroll
    for (int mm = 1; mm < 16; mm <<= 1)
#pragma unroll
      for (int t = 0; t < 4; ++t) {
        sumR[t] += __shfl_xor(sumR[t], mm);
        sumI[t] += __shfl_xor(sumI[t], mm);
      }
    f32x4 fRv, fIv;
#pragma unroll
    for (int t = 0; t < 4; ++t) {
      l_r[t] = l_r[t] * fR[t] + sumR[t];
      l_i[t] = l_i[t] * fI[t] + sumI[t];
      fRv[t] = fR[t]; fIv[t] = fI[t];
    }
#pragma unroll
    for (int n = 0; n < 4; ++n) {
      accA[n] *= fRv; accAi[n] *= fRv;
      accB[n] *= fIv; accBi[n] *= fIv;
    }

    // P writes visible to all lanes of this wave
    asm volatile("s_waitcnt lgkmcnt(0)" ::: "memory");

    // ---- PV ----
    short8 prf[2], pif[2];
#pragma unroll
    for (int kk = 0; kk < 2; ++kk) {
      const int ch = kk * 4 + g;
      const int off = fr * 128 + ((ch ^ (fr & 7)) << 4);
      prf[kk] = *(const short8*)((const char*)pR + off);
      pif[kk] = *(const short8*)((const char*)pI + off);
    }
#pragma unroll
    for (int n = 0; n < 4; ++n) {
      const int d = fr + 16 * n;
#pragma unroll
      for (int kk = 0; kk < 2; ++kk) {
        const int ch = kk * 4 + g;
        const int off = d * 128 + ((ch ^ (d & 7)) << 4);
        short8 vrf = *(const short8*)((const char*)&sVt[0][0][0] + off);
        short8 vif = *(const short8*)((const char*)&sVt[1][0][0] + off);
        accA[n]  = mfma16(prf[kk], vrf, accA[n]);
        accAi[n] = mfma16(prf[kk], vif, accAi[n]);
        accB[n]  = mfma16(pif[kk], vrf, accB[n]);
        accBi[n] = mfma16(pif[kk], vif, accBi[n]);
      }
    }
  }

  // ---- epilogue ----
  float ilr[4], ili[4];
#pragma unroll
  for (int t = 0; t < 4; ++t) { ilr[t] = 1.f / l_r[t]; ili[t] = 1.f / l_i[t]; }
#pragma unroll
  for (int n = 0; n < 4; ++n) {
    const int e = h * 64 + fr + 16 * n;
#pragma unroll
    for (int t = 0; t < 4; ++t) {
      const int sidx = q0 + 16 * w + g * 4 + t;
      const size_t o = ((size_t)b * S_LEN + sidx) * E_SZ + e;
      AOr[o] = f2bf(accA[n][t]  * ilr[t] - accBi[n][t] * ili[t]);
      AOi[o] = f2bf(accAi[n][t] * ilr[t] + accB[n][t]  * ili[t]);
    }
  }
}

extern "C" void kernel_launch(void* const* d_in, const int* in_sizes, int n_in,
                              void* d_out, int out_size, void* d_ws, size_t ws_size,
                              hipStream_t stream)
{
    const float* query_r = (const float*)d_in[0];
    const float* query_i = (const float*)d_in[1];
    const float* key_r   = (const float*)d_in[2];
    const float* key_i   = (const float*)d_in[3];
    const float* value_r = (const float*)d_in[4];
    const float* value_i = (const float*)d_in[5];
    const float* wq_r = (const float*)d_in[6];
    const float* wq_i = (const float*)d_in[7];
    const float* bq_r = (const float*)d_in[8];
    const float* bq_i = (const float*)d_in[9];
    const float* wk_r = (const float*)d_in[10];
    const float* wk_i = (const float*)d_in[11];
    const float* bk_r = (const float*)d_in[12];
    const float* bk_i = (const float*)d_in[13];
    const float* wv_r = (const float*)d_in[14];
    const float* wv_i = (const float*)d_in[15];
    const float* bv_r = (const float*)d_in[16];
    const float* bv_i = (const float*)d_in[17];
    const float* wo_r = (const float*)d_in[18];
    const float* wo_i = (const float*)d_in[19];
    const float* bo_r = (const float*)d_in[20];
    const float* bo_i = (const float*)d_in[21];

    // ws: Q(2) K(2) Vt(2) [bf16 N1 each] | weights 8*WELEM bf16 | AO(2)
    ushort* ws   = (ushort*)d_ws;
    ushort* Qr   = ws;
    ushort* Qi   = Qr + (size_t)N1;
    ushort* Kr   = Qi + (size_t)N1;
    ushort* Ki   = Kr + (size_t)N1;
    ushort* Vtr  = Ki + (size_t)N1;
    ushort* Vti  = Vtr + (size_t)N1;
    ushort* Wb   = Vti + (size_t)N1;
    ushort* Wq_r = Wb + 0 * (size_t)WELEM;
    ushort* Wq_i = Wb + 1 * (size_t)WELEM;
    ushort* Wk_r = Wb + 2 * (size_t)WELEM;
    ushort* Wk_i = Wb + 3 * (size_t)WELEM;
    ushort* Wv_r = Wb + 4 * (size_t)WELEM;
    ushort* Wv_i = Wb + 5 * (size_t)WELEM;
    ushort* Wo_r = Wb + 6 * (size_t)WELEM;
    ushort* Wo_i = Wb + 7 * (size_t)WELEM;
    ushort* AOr  = Wb + 8 * (size_t)WELEM;
    ushort* AOi  = AOr + (size_t)N1;

    cast_w8<<<8192, 256, 0, stream>>>(wq_r, wq_i, wk_r, wk_i,
                                      wv_r, wv_i, wo_r, wo_i, Wb);

    dim3 gg(E_SZ / 128, (S_LEN * B_SZ) / 128);
    cgemm_in<false><<<gg, 256, 0, stream>>>(query_r, query_i, Wq_r, Wq_i, bq_r, bq_i, Qr, Qi);
    cgemm_in<false><<<gg, 256, 0, stream>>>(key_r,   key_i,   Wk_r, Wk_i, bk_r, bk_i, Kr, Ki);
    cgemm_in<true ><<<gg, 256, 0, stream>>>(value_r, value_i, Wv_r, Wv_i, bv_r, bv_i, Vtr, Vti);

    cattn_mfma<<<dim3(S_LEN / 64, B_SZ * H_CNT), 256, 0, stream>>>(
        Qr, Qi, Kr, Ki, Vtr, Vti, AOr, AOi);

    cgemm_o<<<gg, 256, 0, stream>>>(AOr, AOi, Wo_r, Wo_i, bo_r, bo_i, (float*)d_out);
}

// Round 4
// 428.370 us; speedup vs baseline: 19.5054x; 1.1752x over previous
//
#include <hip/hip_runtime.h>
#include <hip/hip_bf16.h>
#include <stdint.h>

#define S_LEN 1024
#define B_SZ  4
#define E_SZ  1024
#define H_CNT 16
#define D_HD  64
#define N1    (B_SZ * H_CNT * S_LEN * D_HD)   // 4194304 elements per component
#define WELEM (E_SZ * E_SZ)                   // 1048576

typedef __attribute__((ext_vector_type(8))) short short8;
typedef __attribute__((ext_vector_type(4))) float f32x4;

__device__ __forceinline__ ushort f2bf(float f) {
  union { float f; uint32_t u; } v; v.f = f;
  uint32_t u = v.u;
  uint32_t r = (u + 0x7fffu + ((u >> 16) & 1u)) >> 16;  // RNE
  return (ushort)r;
}
__device__ __forceinline__ float bf2f(ushort u) {
  union { uint32_t u; float f; } v; v.u = ((uint32_t)u) << 16;
  return v.f;
}
__device__ __forceinline__ short8 pack8(float4 a, float4 b) {
  short8 r;
  r[0] = (short)f2bf(a.x); r[1] = (short)f2bf(a.y);
  r[2] = (short)f2bf(a.z); r[3] = (short)f2bf(a.w);
  r[4] = (short)f2bf(b.x); r[5] = (short)f2bf(b.y);
  r[6] = (short)f2bf(b.z); r[7] = (short)f2bf(b.w);
  return r;
}
static __device__ __forceinline__ f32x4 mfma16(short8 a, short8 b, f32x4 c) {
  return __builtin_amdgcn_mfma_f32_16x16x32_bf16(a, b, c, 0, 0, 0);
}

typedef const __attribute__((address_space(1))) void gv_t;
typedef __attribute__((address_space(3))) void lv_t;
__device__ __forceinline__ void gld16(const void* g, void* l) {
  __builtin_amdgcn_global_load_lds((gv_t*)g, (lv_t*)l, 16, 0, 0);
}

// ---------------------------------------------------------------------------
// Cast 8 fp32 weight matrices [E,E] to bf16, concatenated into dst.
// ---------------------------------------------------------------------------
__global__ __launch_bounds__(256) void cast_w8(
    const float* __restrict__ s0, const float* __restrict__ s1,
    const float* __restrict__ s2, const float* __restrict__ s3,
    const float* __restrict__ s4, const float* __restrict__ s5,
    const float* __restrict__ s6, const float* __restrict__ s7,
    ushort* __restrict__ dst)
{
  const size_t i = (size_t)blockIdx.x * blockDim.x + threadIdx.x;
  const size_t e = i * 4;
  const int which = (int)(e >> 20);
  const size_t off = e & (WELEM - 1);
  const float* s = which < 4
      ? (which < 2 ? (which == 0 ? s0 : s1) : (which == 2 ? s2 : s3))
      : (which < 6 ? (which == 4 ? s4 : s5) : (which == 6 ? s6 : s7));
  const float4 f = *(const float4*)(s + off);
  ushort4 u;
  u.x = f2bf(f.x); u.y = f2bf(f.y); u.z = f2bf(f.z); u.w = f2bf(f.w);
  *(ushort4*)(dst + e) = u;
}

// ---------------------------------------------------------------------------
// Complex bf16 MFMA GEMM for input projections.
//   y = (x @ W^T + bias) * scale   (scale folds the 1/sqrt(D) into Q)
// VT=false: output [B,H,S,D] (Q,K).  VT=true: output [B,H,D,S] (V transposed).
// ---------------------------------------------------------------------------
template<bool VT>
__global__ __launch_bounds__(256) void cgemm_in(
    const float* __restrict__ xr, const float* __restrict__ xi,
    const ushort* __restrict__ wre, const ushort* __restrict__ wim,
    const float* __restrict__ bre, const float* __restrict__ bim,
    ushort* __restrict__ yr, ushort* __restrict__ yi, float scale)
{
  __shared__ __align__(16) ushort sAr[128][32], sAi[128][32], sBr[128][32], sBi[128][32];
  const int tid  = threadIdx.x;
  const int lane = tid & 63;
  const int wid  = tid >> 6;
  const int wrow = wid >> 1, wcol = wid & 1;
  const int fr = lane & 15, fq = lane >> 4;
  const int m0 = blockIdx.y * 128, n0 = blockIdx.x * 128;
  const int srow = tid >> 1;
  const int scol = (tid & 1) * 16;

  f32x4 accR[4][4] = {}, accI[4][4] = {};

  for (int kt = 0; kt < E_SZ / 32; ++kt) {
    const int k0 = kt * 32;
    const float4* par = (const float4*)&xr[(size_t)(m0 + srow) * E_SZ + k0 + scol];
    const float4* pai = (const float4*)&xi[(size_t)(m0 + srow) * E_SZ + k0 + scol];
    float4 fr0 = par[0], fr1 = par[1], fr2 = par[2], fr3 = par[3];
    float4 fi0 = pai[0], fi1 = pai[1], fi2 = pai[2], fi3 = pai[3];
    const short8* pbr = (const short8*)&wre[(size_t)(n0 + srow) * E_SZ + k0 + scol];
    const short8* pbi = (const short8*)&wim[(size_t)(n0 + srow) * E_SZ + k0 + scol];
    short8 wbr0 = pbr[0], wbr1 = pbr[1];
    short8 wbi0 = pbi[0], wbi1 = pbi[1];
    short8 war0 = pack8(fr0, fr1), war1 = pack8(fr2, fr3);
    short8 wai0 = pack8(fi0, fi1), wai1 = pack8(fi2, fi3);

    __syncthreads();
    *(short8*)&sAr[srow][scol]     = war0;
    *(short8*)&sAr[srow][scol + 8] = war1;
    *(short8*)&sAi[srow][scol]     = wai0;
    *(short8*)&sAi[srow][scol + 8] = wai1;
    *(short8*)&sBr[srow][scol]     = wbr0;
    *(short8*)&sBr[srow][scol + 8] = wbr1;
    *(short8*)&sBi[srow][scol]     = wbi0;
    *(short8*)&sBi[srow][scol + 8] = wbi1;
    __syncthreads();

    short8 a_r[4], a_i[4], a_n[4], b_r[4], b_i[4];
#pragma unroll
    for (int mi = 0; mi < 4; ++mi) {
      a_r[mi] = *(const short8*)&sAr[wrow * 64 + mi * 16 + fr][fq * 8];
      a_i[mi] = *(const short8*)&sAi[wrow * 64 + mi * 16 + fr][fq * 8];
      a_n[mi] = a_i[mi] ^ (short)0x8000;
    }
#pragma unroll
    for (int ni = 0; ni < 4; ++ni) {
      b_r[ni] = *(const short8*)&sBr[wcol * 64 + ni * 16 + fr][fq * 8];
      b_i[ni] = *(const short8*)&sBi[wcol * 64 + ni * 16 + fr][fq * 8];
    }
#pragma unroll
    for (int mi = 0; mi < 4; ++mi)
#pragma unroll
      for (int ni = 0; ni < 4; ++ni) {
        accR[mi][ni] = mfma16(a_r[mi], b_r[ni], accR[mi][ni]);
        accR[mi][ni] = mfma16(a_n[mi], b_i[ni], accR[mi][ni]);
        accI[mi][ni] = mfma16(a_r[mi], b_i[ni], accI[mi][ni]);
        accI[mi][ni] = mfma16(a_i[mi], b_r[ni], accI[mi][ni]);
      }
  }

#pragma unroll
  for (int ni = 0; ni < 4; ++ni) {
    const int n = n0 + wcol * 64 + ni * 16 + fr;
    const float bR = bre[n], bI = bim[n];
    const int h = n >> 6, d = n & 63;
#pragma unroll
    for (int mi = 0; mi < 4; ++mi) {
      const int mb = m0 + wrow * 64 + mi * 16 + fq * 4;
#pragma unroll
      for (int q = 0; q < 4; ++q) {
        const int m = mb + q;
        const int s = m >> 2, b = m & 3;      // m = s*B + b
        size_t o;
        if (!VT) o = (((size_t)(b * H_CNT + h) * S_LEN) + s) * D_HD + d;
        else     o = (((size_t)(b * H_CNT + h) * D_HD) + d) * S_LEN + s;
        yr[o] = f2bf((accR[mi][ni][q] + bR) * scale);
        yi[o] = f2bf((accI[mi][ni][q] + bI) * scale);
      }
    }
  }
}

// ---------------------------------------------------------------------------
// Output projection: A = AO (bf16 [B,S,E], row m = b*S+s), out fp32 [S,B,E,2].
// ---------------------------------------------------------------------------
__global__ __launch_bounds__(256) void cgemm_o(
    const ushort* __restrict__ aor, const ushort* __restrict__ aoi,
    const ushort* __restrict__ wre, const ushort* __restrict__ wim,
    const float* __restrict__ bre, const float* __restrict__ bim,
    float* __restrict__ out)
{
  __shared__ __align__(16) ushort sAr[128][32], sAi[128][32], sBr[128][32], sBi[128][32];
  const int tid  = threadIdx.x;
  const int lane = tid & 63;
  const int wid  = tid >> 6;
  const int wrow = wid >> 1, wcol = wid & 1;
  const int fr = lane & 15, fq = lane >> 4;
  const int m0 = blockIdx.y * 128, n0 = blockIdx.x * 128;
  const int srow = tid >> 1;
  const int scol = (tid & 1) * 16;

  f32x4 accR[4][4] = {}, accI[4][4] = {};

  for (int kt = 0; kt < E_SZ / 32; ++kt) {
    const int k0 = kt * 32;
    const short8* par = (const short8*)&aor[(size_t)(m0 + srow) * E_SZ + k0 + scol];
    const short8* pai = (const short8*)&aoi[(size_t)(m0 + srow) * E_SZ + k0 + scol];
    short8 war0 = par[0], war1 = par[1];
    short8 wai0 = pai[0], wai1 = pai[1];
    const short8* pbr = (const short8*)&wre[(size_t)(n0 + srow) * E_SZ + k0 + scol];
    const short8* pbi = (const short8*)&wim[(size_t)(n0 + srow) * E_SZ + k0 + scol];
    short8 wbr0 = pbr[0], wbr1 = pbr[1];
    short8 wbi0 = pbi[0], wbi1 = pbi[1];

    __syncthreads();
    *(short8*)&sAr[srow][scol]     = war0;
    *(short8*)&sAr[srow][scol + 8] = war1;
    *(short8*)&sAi[srow][scol]     = wai0;
    *(short8*)&sAi[srow][scol + 8] = wai1;
    *(short8*)&sBr[srow][scol]     = wbr0;
    *(short8*)&sBr[srow][scol + 8] = wbr1;
    *(short8*)&sBi[srow][scol]     = wbi0;
    *(short8*)&sBi[srow][scol + 8] = wbi1;
    __syncthreads();

    short8 a_r[4], a_i[4], a_n[4], b_r[4], b_i[4];
#pragma unroll
    for (int mi = 0; mi < 4; ++mi) {
      a_r[mi] = *(const short8*)&sAr[wrow * 64 + mi * 16 + fr][fq * 8];
      a_i[mi] = *(const short8*)&sAi[wrow * 64 + mi * 16 + fr][fq * 8];
      a_n[mi] = a_i[mi] ^ (short)0x8000;
    }
#pragma unroll
    for (int ni = 0; ni < 4; ++ni) {
      b_r[ni] = *(const short8*)&sBr[wcol * 64 + ni * 16 + fr][fq * 8];
      b_i[ni] = *(const short8*)&sBi[wcol * 64 + ni * 16 + fr][fq * 8];
    }
#pragma unroll
    for (int mi = 0; mi < 4; ++mi)
#pragma unroll
      for (int ni = 0; ni < 4; ++ni) {
        accR[mi][ni] = mfma16(a_r[mi], b_r[ni], accR[mi][ni]);
        accR[mi][ni] = mfma16(a_n[mi], b_i[ni], accR[mi][ni]);
        accI[mi][ni] = mfma16(a_r[mi], b_i[ni], accI[mi][ni]);
        accI[mi][ni] = mfma16(a_i[mi], b_r[ni], accI[mi][ni]);
      }
  }

#pragma unroll
  for (int ni = 0; ni < 4; ++ni) {
    const int n = n0 + wcol * 64 + ni * 16 + fr;
    const float bR = bre[n], bI = bim[n];
#pragma unroll
    for (int mi = 0; mi < 4; ++mi) {
      const int mb = m0 + wrow * 64 + mi * 16 + fq * 4;
#pragma unroll
      for (int q = 0; q < 4; ++q) {
        const int m = mb + q;
        const int b = m >> 10, s = m & 1023;  // m = b*S + s
        const size_t o = (((size_t)(s * B_SZ + b) * E_SZ) + n) * 2;
        out[o]     = accR[mi][ni][q] + bR;
        out[o + 1] = accI[mi][ni][q] + bI;
      }
    }
  }
}

// ---------------------------------------------------------------------------
// MFMA complex flash attention, split softmax WITHOUT max tracking
// (scores are O(3) max -> exp() safe; 1/8 scale pre-folded into Q).
// grid (S/128, B*H), 256 threads = 4 waves; wave w owns q-rows [q0+32w, +32).
// Q,K: bf16 [BH,S,D] (Q pre-scaled by 1/8); Vt: bf16 [BH,D,S]; AO: bf16 [B,S,E].
// K/V staged via global_load_lds with pre-swizzled global source so that
// LDS chunk c at row r holds global chunk c^(r&7)  (conflict-free reads).
// ---------------------------------------------------------------------------
__global__ __launch_bounds__(256) void cattn_mfma(
    const ushort* __restrict__ Qr, const ushort* __restrict__ Qi,
    const ushort* __restrict__ Kr, const ushort* __restrict__ Ki,
    const ushort* __restrict__ Vtr, const ushort* __restrict__ Vti,
    ushort* __restrict__ AOr, ushort* __restrict__ AOi)
{
  __shared__ __align__(16) ushort sK[2][64][64];    // [comp][k][d]   8KB each
  __shared__ __align__(16) ushort sVt[2][64][64];   // [comp][d][k]
  __shared__ __align__(16) ushort sP[4][2][32][64]; // [wave][comp][q][k]

  const int tid  = threadIdx.x;
  const int lane = tid & 63;
  const int w    = tid >> 6;
  const int g    = lane >> 4;
  const int fr   = lane & 15;
  const int bh   = blockIdx.y;
  const int b    = bh >> 4, h = bh & 15;
  const int q0   = blockIdx.x * 128;
  const int qw   = q0 + 32 * w;

  // Q fragments: rows qw + hq*16 + fr, k-slices kk*32 + g*8
  short8 qfr[2][2], qfi[2][2];
#pragma unroll
  for (int hq = 0; hq < 2; ++hq) {
    const size_t qrow = ((size_t)bh * S_LEN + qw + hq * 16 + fr) * D_HD;
#pragma unroll
    for (int kk = 0; kk < 2; ++kk) {
      qfr[hq][kk] = *(const short8*)(Qr + qrow + kk * 32 + g * 8);
      qfi[hq][kk] = *(const short8*)(Qi + qrow + kk * 32 + g * 8);
    }
  }

  // staging: wave w owns one buffer; lane fetches pre-swizzled global chunk
  const int lrow8 = lane >> 3;          // row offset within 8-row group
  const int sch   = (lane & 7) ^ lrow8; // source chunk (involution)
  const ushort* gsrc; ushort* sdst;
  if      (w == 0) { gsrc = Kr  + (size_t)bh * S_LEN * D_HD; sdst = &sK[0][0][0]; }
  else if (w == 1) { gsrc = Ki  + (size_t)bh * S_LEN * D_HD; sdst = &sK[1][0][0]; }
  else if (w == 2) { gsrc = Vtr + (size_t)bh * D_HD * S_LEN; sdst = &sVt[0][0][0]; }
  else             { gsrc = Vti + (size_t)bh * D_HD * S_LEN; sdst = &sVt[1][0][0]; }
  const bool isK = (w < 2);

  f32x4 accA[2][4] = {}, accAi[2][4] = {}, accB[2][4] = {}, accBi[2][4] = {};
  f32x4 lpr[2] = {}, lpi[2] = {};   // per-lane partial softmax denominators

  ushort* pR = &sP[w][0][0][0];
  ushort* pI = &sP[w][1][0][0];
  const int par  = fr & 1;
  const int k0b  = fr & ~1;
  ushort* pbuf   = par ? pI : pR;
  const int woff = (k0b * 2) & 15;      // byte offset within 16B chunk

  for (int kt = 0; kt < 16; ++kt) {
    __syncthreads();   // prev tile fully consumed by all waves
    if (isK) {
      const ushort* gp = gsrc + (size_t)kt * 4096 + lrow8 * 64 + sch * 8;
#pragma unroll
      for (int i = 0; i < 8; ++i)
        gld16(gp + i * 512, (char*)sdst + i * 1024);
    } else {
      const ushort* gp = gsrc + (size_t)lrow8 * S_LEN + kt * 64 + sch * 8;
#pragma unroll
      for (int i = 0; i < 8; ++i)
        gld16(gp + (size_t)i * 8 * S_LEN, (char*)sdst + i * 1024);
    }
    __syncthreads();   // vmcnt drained by barrier: tile ready

    // ---- QK^T ----
    f32x4 Sr[2][4] = {}, Si[2][4] = {};
#pragma unroll
    for (int n = 0; n < 4; ++n) {
      const int kc = fr + 16 * n;
      const int rb = kc * 128, sw = (kc & 7) << 4;
#pragma unroll
      for (int kk = 0; kk < 2; ++kk) {
        const int off = rb + ((((kk * 4 + g) << 4)) ^ sw);
        short8 krf = *(const short8*)((const char*)&sK[0][0][0] + off);
        short8 kif = *(const short8*)((const char*)&sK[1][0][0] + off);
        short8 kin = kif ^ (short)0x8000;
#pragma unroll
        for (int hq = 0; hq < 2; ++hq) {
          Sr[hq][n] = mfma16(qfr[hq][kk], krf, Sr[hq][n]);
          Sr[hq][n] = mfma16(qfi[hq][kk], kin, Sr[hq][n]);
          Si[hq][n] = mfma16(qfr[hq][kk], kif, Si[hq][n]);
          Si[hq][n] = mfma16(qfi[hq][kk], krf, Si[hq][n]);
        }
      }
    }

    // ---- softmax numerators (no max subtraction) + pair-packed P write ----
#pragma unroll
    for (int hq = 0; hq < 2; ++hq)
#pragma unroll
      for (int n = 0; n < 4; ++n) {
        const int cbase = (k0b + 16 * n) >> 3;
#pragma unroll
        for (int t = 0; t < 4; ++t) {
          float pr = __expf(Sr[hq][n][t]);
          float pi = __expf(Si[hq][n][t]);
          lpr[hq][t] += pr; lpi[hq][t] += pi;
          float pro = __shfl_xor(pr, 1);
          float pio = __shfl_xor(pi, 1);
          float lo = par ? pio : pr;
          float hi = par ? pi  : pro;
          uint32_t pk;
          asm("v_cvt_pk_bf16_f32 %0, %1, %2" : "=v"(pk) : "v"(lo), "v"(hi));
          const int q = hq * 16 + g * 4 + t;
          const int off = q * 128 + ((cbase ^ (q & 7)) << 4) + woff;
          *(uint32_t*)((char*)pbuf + off) = pk;
        }
      }
    asm volatile("s_waitcnt lgkmcnt(0)" ::: "memory");

    // ---- PV ----
    short8 prf[2][2], pif[2][2];
#pragma unroll
    for (int hq = 0; hq < 2; ++hq)
#pragma unroll
      for (int kk = 0; kk < 2; ++kk) {
        const int off = (hq * 16 + fr) * 128 + ((((kk * 4 + g) << 4)) ^ ((fr & 7) << 4));
        prf[hq][kk] = *(const short8*)((const char*)pR + off);
        pif[hq][kk] = *(const short8*)((const char*)pI + off);
      }
#pragma unroll
    for (int n = 0; n < 4; ++n) {
      const int d = fr + 16 * n;
      const int rb = d * 128, sw = (d & 7) << 4;
#pragma unroll
      for (int kk = 0; kk < 2; ++kk) {
        const int off = rb + ((((kk * 4 + g) << 4)) ^ sw);
        short8 vrf = *(const short8*)((const char*)&sVt[0][0][0] + off);
        short8 vif = *(const short8*)((const char*)&sVt[1][0][0] + off);
#pragma unroll
        for (int hq = 0; hq < 2; ++hq) {
          accA [hq][n] = mfma16(prf[hq][kk], vrf, accA [hq][n]);
          accAi[hq][n] = mfma16(prf[hq][kk], vif, accAi[hq][n]);
          accB [hq][n] = mfma16(pif[hq][kk], vrf, accB [hq][n]);
          accBi[hq][n] = mfma16(pif[hq][kk], vif, accBi[hq][n]);
        }
      }
    }
  }

  // ---- final denominator reduce (once, not per tile) ----
#pragma unroll
  for (int mm = 1; mm < 16; mm <<= 1)
#pragma unroll
    for (int hq = 0; hq < 2; ++hq)
#pragma unroll
      for (int t = 0; t < 4; ++t) {
        lpr[hq][t] += __shfl_xor(lpr[hq][t], mm);
        lpi[hq][t] += __shfl_xor(lpi[hq][t], mm);
      }

  // ---- epilogue ----
#pragma unroll
  for (int hq = 0; hq < 2; ++hq) {
    f32x4 ilr, ili;
#pragma unroll
    for (int t = 0; t < 4; ++t) { ilr[t] = 1.f / lpr[hq][t]; ili[t] = 1.f / lpi[hq][t]; }
#pragma unroll
    for (int n = 0; n < 4; ++n) {
      const int e = h * 64 + fr + 16 * n;
#pragma unroll
      for (int t = 0; t < 4; ++t) {
        const int sidx = qw + hq * 16 + g * 4 + t;
        const size_t o = ((size_t)b * S_LEN + sidx) * E_SZ + e;
        AOr[o] = f2bf(accA [hq][n][t] * ilr[t] - accBi[hq][n][t] * ili[t]);
        AOi[o] = f2bf(accAi[hq][n][t] * ilr[t] + accB [hq][n][t] * ili[t]);
      }
    }
  }
}

extern "C" void kernel_launch(void* const* d_in, const int* in_sizes, int n_in,
                              void* d_out, int out_size, void* d_ws, size_t ws_size,
                              hipStream_t stream)
{
    const float* query_r = (const float*)d_in[0];
    const float* query_i = (const float*)d_in[1];
    const float* key_r   = (const float*)d_in[2];
    const float* key_i   = (const float*)d_in[3];
    const float* value_r = (const float*)d_in[4];
    const float* value_i = (const float*)d_in[5];
    const float* wq_r = (const float*)d_in[6];
    const float* wq_i = (const float*)d_in[7];
    const float* bq_r = (const float*)d_in[8];
    const float* bq_i = (const float*)d_in[9];
    const float* wk_r = (const float*)d_in[10];
    const float* wk_i = (const float*)d_in[11];
    const float* bk_r = (const float*)d_in[12];
    const float* bk_i = (const float*)d_in[13];
    const float* wv_r = (const float*)d_in[14];
    const float* wv_i = (const float*)d_in[15];
    const float* bv_r = (const float*)d_in[16];
    const float* bv_i = (const float*)d_in[17];
    const float* wo_r = (const float*)d_in[18];
    const float* wo_i = (const float*)d_in[19];
    const float* bo_r = (const float*)d_in[20];
    const float* bo_i = (const float*)d_in[21];

    // ws: Q(2) K(2) Vt(2) [bf16 N1 each] | weights 8*WELEM bf16 | AO(2)
    ushort* ws   = (ushort*)d_ws;
    ushort* Qr   = ws;
    ushort* Qi   = Qr + (size_t)N1;
    ushort* Kr   = Qi + (size_t)N1;
    ushort* Ki   = Kr + (size_t)N1;
    ushort* Vtr  = Ki + (size_t)N1;
    ushort* Vti  = Vtr + (size_t)N1;
    ushort* Wb   = Vti + (size_t)N1;
    ushort* Wq_r = Wb + 0 * (size_t)WELEM;
    ushort* Wq_i = Wb + 1 * (size_t)WELEM;
    ushort* Wk_r = Wb + 2 * (size_t)WELEM;
    ushort* Wk_i = Wb + 3 * (size_t)WELEM;
    ushort* Wv_r = Wb + 4 * (size_t)WELEM;
    ushort* Wv_i = Wb + 5 * (size_t)WELEM;
    ushort* Wo_r = Wb + 6 * (size_t)WELEM;
    ushort* Wo_i = Wb + 7 * (size_t)WELEM;
    ushort* AOr  = Wb + 8 * (size_t)WELEM;
    ushort* AOi  = AOr + (size_t)N1;

    cast_w8<<<8192, 256, 0, stream>>>(wq_r, wq_i, wk_r, wk_i,
                                      wv_r, wv_i, wo_r, wo_i, Wb);

    dim3 gg(E_SZ / 128, (S_LEN * B_SZ) / 128);
    cgemm_in<false><<<gg, 256, 0, stream>>>(query_r, query_i, Wq_r, Wq_i, bq_r, bq_i, Qr, Qi, 0.125f);
    cgemm_in<false><<<gg, 256, 0, stream>>>(key_r,   key_i,   Wk_r, Wk_i, bk_r, bk_i, Kr, Ki, 1.0f);
    cgemm_in<true ><<<gg, 256, 0, stream>>>(value_r, value_i, Wv_r, Wv_i, bv_r, bv_i, Vtr, Vti, 1.0f);

    cattn_mfma<<<dim3(S_LEN / 128, B_SZ * H_CNT), 256, 0, stream>>>(
        Qr, Qi, Kr, Ki, Vtr, Vti, AOr, AOi);

    cgemm_o<<<gg, 256, 0, stream>>>(AOr, AOi, Wo_r, Wo_i, bo_r, bo_i, (float*)d_out);
}

// Round 5
// 309.698 us; speedup vs baseline: 26.9797x; 1.3832x over previous
//
#include <hip/hip_runtime.h>
#include <hip/hip_bf16.h>
#include <stdint.h>

#define S_LEN 1024
#define B_SZ  4
#define E_SZ  1024
#define H_CNT 16
#define D_HD  64
#define N1    (B_SZ * H_CNT * S_LEN * D_HD)   // 4194304 elements per component
#define WELEM (E_SZ * E_SZ)                   // 1048576

typedef __attribute__((ext_vector_type(8))) short short8;
typedef __attribute__((ext_vector_type(4))) float f32x4;

__device__ __forceinline__ ushort f2bf(float f) {
  union { float f; uint32_t u; } v; v.f = f;
  uint32_t u = v.u;
  uint32_t r = (u + 0x7fffu + ((u >> 16) & 1u)) >> 16;  // RNE
  return (ushort)r;
}
__device__ __forceinline__ float bf2f(ushort u) {
  union { uint32_t u; float f; } v; v.u = ((uint32_t)u) << 16;
  return v.f;
}
__device__ __forceinline__ short8 pack8(float4 a, float4 b) {
  short8 r;
  r[0] = (short)f2bf(a.x); r[1] = (short)f2bf(a.y);
  r[2] = (short)f2bf(a.z); r[3] = (short)f2bf(a.w);
  r[4] = (short)f2bf(b.x); r[5] = (short)f2bf(b.y);
  r[6] = (short)f2bf(b.z); r[7] = (short)f2bf(b.w);
  return r;
}
static __device__ __forceinline__ f32x4 mfma16(short8 a, short8 b, f32x4 c) {
  return __builtin_amdgcn_mfma_f32_16x16x32_bf16(a, b, c, 0, 0, 0);
}

typedef const __attribute__((address_space(1))) void gv_t;
typedef __attribute__((address_space(3))) void lv_t;
__device__ __forceinline__ void gld16(const void* g, void* l) {
  __builtin_amdgcn_global_load_lds((gv_t*)g, (lv_t*)l, 16, 0, 0);
}

// ---------------------------------------------------------------------------
// Cast 8 fp32 weight matrices [E,E] to bf16, concatenated into dst.
// ---------------------------------------------------------------------------
__global__ __launch_bounds__(256) void cast_w8(
    const float* __restrict__ s0, const float* __restrict__ s1,
    const float* __restrict__ s2, const float* __restrict__ s3,
    const float* __restrict__ s4, const float* __restrict__ s5,
    const float* __restrict__ s6, const float* __restrict__ s7,
    ushort* __restrict__ dst)
{
  const size_t i = (size_t)blockIdx.x * blockDim.x + threadIdx.x;
  const size_t e = i * 4;
  const int which = (int)(e >> 20);
  const size_t off = e & (WELEM - 1);
  const float* s = which < 4
      ? (which < 2 ? (which == 0 ? s0 : s1) : (which == 2 ? s2 : s3))
      : (which < 6 ? (which == 4 ? s4 : s5) : (which == 6 ? s6 : s7));
  const float4 f = *(const float4*)(s + off);
  ushort4 u;
  u.x = f2bf(f.x); u.y = f2bf(f.y); u.z = f2bf(f.z); u.w = f2bf(f.w);
  *(ushort4*)(dst + e) = u;
}

// ---------------------------------------------------------------------------
// Cast one complex activation pair [S,B,E] fp32 -> bf16 (8 elems/thread).
// grid N1/(8*256) = 2048 blocks.
// ---------------------------------------------------------------------------
__global__ __launch_bounds__(256) void castA(
    const float* __restrict__ xr, const float* __restrict__ xi,
    ushort* __restrict__ yr, ushort* __restrict__ yi)
{
  const size_t e = ((size_t)blockIdx.x * 256 + threadIdx.x) * 8;
  float4 a = *(const float4*)(xr + e);
  float4 b = *(const float4*)(xr + e + 4);
  *(short8*)(yr + e) = pack8(a, b);
  a = *(const float4*)(xi + e);
  b = *(const float4*)(xi + e + 4);
  *(short8*)(yi + e) = pack8(a, b);
}

// ---------------------------------------------------------------------------
// Unified complex bf16 MFMA GEMM:  Y = (A @ W^T + bias) * scale
//   A: bf16 [4096,1024] row-major;  W: bf16 [1024,1024] row-major [out,in]
// Tile BM=128 x BN=64, BK=64; 256 threads = 4 waves (2x2), wave tile 64x32.
// Staging: global_load_lds w=16, pre-swizzled source chunk (c ^ row&7),
// LDS [rows][64] bf16, read with same XOR -> 2-way (free) bank access.
// MODE 0: out bf16 [B,H,S,D] (row m = s*B+b)    (Q, K; scale folds 1/8 for Q)
// MODE 1: out bf16 [B,H,D,S] (V transposed)
// MODE 2: out fp32 [S,B,E,2] interleaved (row m = b*S+s), scale=1
// ---------------------------------------------------------------------------
template<int MODE>
__global__ __launch_bounds__(256) void cgemm(
    const ushort* __restrict__ ar_, const ushort* __restrict__ ai_,
    const ushort* __restrict__ wre, const ushort* __restrict__ wim,
    const float* __restrict__ bre, const float* __restrict__ bim,
    ushort* __restrict__ yr, ushort* __restrict__ yi,
    float* __restrict__ outf, float scale)
{
  __shared__ __align__(16) ushort sAr[128 * 64], sAi[128 * 64];
  __shared__ __align__(16) ushort sBr[64 * 64],  sBi[64 * 64];

  const int tid  = threadIdx.x;
  const int lane = tid & 63;
  const int w    = tid >> 6;
  const int wrow = w >> 1, wcol = w & 1;
  const int fr   = lane & 15, fq = lane >> 4;

  // bijective XCD swizzle over 512 workgroups (512 % 8 == 0)
  const int flat = blockIdx.x + gridDim.x * blockIdx.y;
  const int swz  = (flat & 7) * 64 + (flat >> 3);
  const int n0   = (swz & 15) * 64;    // 16 n-tiles of 64
  const int m0   = (swz >> 4) * 128;   // 32 m-tiles of 128

  // staging: wave w owns one buffer
  const ushort* gbase = (w == 0) ? ar_ : (w == 1) ? ai_ : (w == 2) ? wre : wim;
  char* sbase = (w == 0) ? (char*)sAr : (w == 1) ? (char*)sAi
              : (w == 2) ? (char*)sBr : (char*)sBi;
  const int rbase = (w < 2) ? m0 : n0;
  const int lrow  = lane >> 3;            // 0..7
  const int sch   = (lane & 7) ^ lrow;    // pre-swizzled source chunk
  const ushort* gp0 = gbase + (size_t)(rbase + lrow) * E_SZ + sch * 8;

  f32x4 accR[4][2] = {}, accI[4][2] = {};

  for (int kt = 0; kt < 16; ++kt) {
    const int k0 = kt * 64;
    __syncthreads();   // previous tile fully consumed
    if (w < 2) {
#pragma unroll
      for (int i = 0; i < 16; ++i)
        gld16(gp0 + (size_t)i * 8 * E_SZ + k0, sbase + i * 1024);
    } else {
#pragma unroll
      for (int i = 0; i < 8; ++i)
        gld16(gp0 + (size_t)i * 8 * E_SZ + k0, sbase + i * 1024);
    }
    __syncthreads();   // vmcnt drained by barrier: tile ready

#pragma unroll
    for (int kk = 0; kk < 2; ++kk) {
      short8 a_r[4], a_i[4], a_n[4], b_r[2], b_i[2];
#pragma unroll
      for (int mi = 0; mi < 4; ++mi) {
        const int row = wrow * 64 + mi * 16 + fr;
        const int off = row * 128 + (((kk * 4 + fq) ^ (row & 7)) << 4);
        a_r[mi] = *(const short8*)((const char*)sAr + off);
        a_i[mi] = *(const short8*)((const char*)sAi + off);
        a_n[mi] = a_i[mi] ^ (short)0x8000;
      }
#pragma unroll
      for (int ni = 0; ni < 2; ++ni) {
        const int row = wcol * 32 + ni * 16 + fr;
        const int off = row * 128 + (((kk * 4 + fq) ^ (row & 7)) << 4);
        b_r[ni] = *(const short8*)((const char*)sBr + off);
        b_i[ni] = *(const short8*)((const char*)sBi + off);
      }
#pragma unroll
      for (int mi = 0; mi < 4; ++mi)
#pragma unroll
        for (int ni = 0; ni < 2; ++ni) {
          accR[mi][ni] = mfma16(a_r[mi], b_r[ni], accR[mi][ni]);
          accR[mi][ni] = mfma16(a_n[mi], b_i[ni], accR[mi][ni]);
          accI[mi][ni] = mfma16(a_r[mi], b_i[ni], accI[mi][ni]);
          accI[mi][ni] = mfma16(a_i[mi], b_r[ni], accI[mi][ni]);
        }
    }
  }

  // epilogue: C/D layout col=lane&15, row=(lane>>4)*4+reg
#pragma unroll
  for (int ni = 0; ni < 2; ++ni) {
    const int n = n0 + wcol * 32 + ni * 16 + fr;
    const float bR = bre[n], bI = bim[n];
    const int h = n >> 6, d = n & 63;
#pragma unroll
    for (int mi = 0; mi < 4; ++mi) {
      const int mb = m0 + wrow * 64 + mi * 16 + fq * 4;
#pragma unroll
      for (int q = 0; q < 4; ++q) {
        const int m = mb + q;
        const float vr = (accR[mi][ni][q] + bR) * scale;
        const float vi = (accI[mi][ni][q] + bI) * scale;
        if (MODE == 0) {
          const int s = m >> 2, b = m & 3;   // m = s*B + b
          const size_t o = (((size_t)(b * H_CNT + h) * S_LEN) + s) * D_HD + d;
          yr[o] = f2bf(vr); yi[o] = f2bf(vi);
        } else if (MODE == 1) {
          const int s = m >> 2, b = m & 3;
          const size_t o = (((size_t)(b * H_CNT + h) * D_HD) + d) * S_LEN + s;
          yr[o] = f2bf(vr); yi[o] = f2bf(vi);
        } else {
          const int b = m >> 10, s = m & 1023;  // m = b*S + s
          const size_t o = (((size_t)(s * B_SZ + b) * E_SZ) + n) * 2;
          outf[o] = vr; outf[o + 1] = vi;
        }
      }
    }
  }
}

// ---------------------------------------------------------------------------
// MFMA complex flash attention, split softmax WITHOUT max tracking
// (scores are O(3) max -> exp() safe; 1/8 scale pre-folded into Q).
// grid (S/128, B*H), 256 threads = 4 waves; wave w owns q-rows [q0+32w, +32).
// ---------------------------------------------------------------------------
__global__ __launch_bounds__(256) void cattn_mfma(
    const ushort* __restrict__ Qr, const ushort* __restrict__ Qi,
    const ushort* __restrict__ Kr, const ushort* __restrict__ Ki,
    const ushort* __restrict__ Vtr, const ushort* __restrict__ Vti,
    ushort* __restrict__ AOr, ushort* __restrict__ AOi)
{
  __shared__ __align__(16) ushort sK[2][64][64];    // [comp][k][d]   8KB each
  __shared__ __align__(16) ushort sVt[2][64][64];   // [comp][d][k]
  __shared__ __align__(16) ushort sP[4][2][32][64]; // [wave][comp][q][k]

  const int tid  = threadIdx.x;
  const int lane = tid & 63;
  const int w    = tid >> 6;
  const int g    = lane >> 4;
  const int fr   = lane & 15;
  const int bh   = blockIdx.y;
  const int b    = bh >> 4, h = bh & 15;
  const int q0   = blockIdx.x * 128;
  const int qw   = q0 + 32 * w;

  // Q fragments: rows qw + hq*16 + fr, k-slices kk*32 + g*8
  short8 qfr[2][2], qfi[2][2];
#pragma unroll
  for (int hq = 0; hq < 2; ++hq) {
    const size_t qrow = ((size_t)bh * S_LEN + qw + hq * 16 + fr) * D_HD;
#pragma unroll
    for (int kk = 0; kk < 2; ++kk) {
      qfr[hq][kk] = *(const short8*)(Qr + qrow + kk * 32 + g * 8);
      qfi[hq][kk] = *(const short8*)(Qi + qrow + kk * 32 + g * 8);
    }
  }

  // staging: wave w owns one buffer; lane fetches pre-swizzled global chunk
  const int lrow8 = lane >> 3;          // row offset within 8-row group
  const int sch   = (lane & 7) ^ lrow8; // source chunk (involution)
  const ushort* gsrc; ushort* sdst;
  if      (w == 0) { gsrc = Kr  + (size_t)bh * S_LEN * D_HD; sdst = &sK[0][0][0]; }
  else if (w == 1) { gsrc = Ki  + (size_t)bh * S_LEN * D_HD; sdst = &sK[1][0][0]; }
  else if (w == 2) { gsrc = Vtr + (size_t)bh * D_HD * S_LEN; sdst = &sVt[0][0][0]; }
  else             { gsrc = Vti + (size_t)bh * D_HD * S_LEN; sdst = &sVt[1][0][0]; }
  const bool isK = (w < 2);

  f32x4 accA[2][4] = {}, accAi[2][4] = {}, accB[2][4] = {}, accBi[2][4] = {};
  f32x4 lpr[2] = {}, lpi[2] = {};   // per-lane partial softmax denominators

  ushort* pR = &sP[w][0][0][0];
  ushort* pI = &sP[w][1][0][0];
  const int par  = fr & 1;
  const int k0b  = fr & ~1;
  ushort* pbuf   = par ? pI : pR;
  const int woff = (k0b * 2) & 15;      // byte offset within 16B chunk

  for (int kt = 0; kt < 16; ++kt) {
    __syncthreads();   // prev tile fully consumed by all waves
    if (isK) {
      const ushort* gp = gsrc + (size_t)kt * 4096 + lrow8 * 64 + sch * 8;
#pragma unroll
      for (int i = 0; i < 8; ++i)
        gld16(gp + i * 512, (char*)sdst + i * 1024);
    } else {
      const ushort* gp = gsrc + (size_t)lrow8 * S_LEN + kt * 64 + sch * 8;
#pragma unroll
      for (int i = 0; i < 8; ++i)
        gld16(gp + (size_t)i * 8 * S_LEN, (char*)sdst + i * 1024);
    }
    __syncthreads();   // vmcnt drained by barrier: tile ready

    // ---- QK^T ----
    f32x4 Sr[2][4] = {}, Si[2][4] = {};
#pragma unroll
    for (int n = 0; n < 4; ++n) {
      const int kc = fr + 16 * n;
      const int rb = kc * 128, sw = (kc & 7) << 4;
#pragma unroll
      for (int kk = 0; kk < 2; ++kk) {
        const int off = rb + ((((kk * 4 + g) << 4)) ^ sw);
        short8 krf = *(const short8*)((const char*)&sK[0][0][0] + off);
        short8 kif = *(const short8*)((const char*)&sK[1][0][0] + off);
        short8 kin = kif ^ (short)0x8000;
#pragma unroll
        for (int hq = 0; hq < 2; ++hq) {
          Sr[hq][n] = mfma16(qfr[hq][kk], krf, Sr[hq][n]);
          Sr[hq][n] = mfma16(qfi[hq][kk], kin, Sr[hq][n]);
          Si[hq][n] = mfma16(qfr[hq][kk], kif, Si[hq][n]);
          Si[hq][n] = mfma16(qfi[hq][kk], krf, Si[hq][n]);
        }
      }
    }

    // ---- softmax numerators (no max subtraction) + pair-packed P write ----
#pragma unroll
    for (int hq = 0; hq < 2; ++hq)
#pragma unroll
      for (int n = 0; n < 4; ++n) {
        const int cbase = (k0b + 16 * n) >> 3;
#pragma unroll
        for (int t = 0; t < 4; ++t) {
          float pr = __expf(Sr[hq][n][t]);
          float pi = __expf(Si[hq][n][t]);
          lpr[hq][t] += pr; lpi[hq][t] += pi;
          float pro = __shfl_xor(pr, 1);
          float pio = __shfl_xor(pi, 1);
          float lo = par ? pio : pr;
          float hi = par ? pi  : pro;
          uint32_t pk;
          asm("v_cvt_pk_bf16_f32 %0, %1, %2" : "=v"(pk) : "v"(lo), "v"(hi));
          const int q = hq * 16 + g * 4 + t;
          const int off = q * 128 + ((cbase ^ (q & 7)) << 4) + woff;
          *(uint32_t*)((char*)pbuf + off) = pk;
        }
      }
    asm volatile("s_waitcnt lgkmcnt(0)" ::: "memory");

    // ---- PV ----
    short8 prf[2][2], pif[2][2];
#pragma unroll
    for (int hq = 0; hq < 2; ++hq)
#pragma unroll
      for (int kk = 0; kk < 2; ++kk) {
        const int off = (hq * 16 + fr) * 128 + ((((kk * 4 + g) << 4)) ^ ((fr & 7) << 4));
        prf[hq][kk] = *(const short8*)((const char*)pR + off);
        pif[hq][kk] = *(const short8*)((const char*)pI + off);
      }
#pragma unroll
    for (int n = 0; n < 4; ++n) {
      const int d = fr + 16 * n;
      const int rb = d * 128, sw = (d & 7) << 4;
#pragma unroll
      for (int kk = 0; kk < 2; ++kk) {
        const int off = rb + ((((kk * 4 + g) << 4)) ^ sw);
        short8 vrf = *(const short8*)((const char*)&sVt[0][0][0] + off);
        short8 vif = *(const short8*)((const char*)&sVt[1][0][0] + off);
#pragma unroll
        for (int hq = 0; hq < 2; ++hq) {
          accA [hq][n] = mfma16(prf[hq][kk], vrf, accA [hq][n]);
          accAi[hq][n] = mfma16(prf[hq][kk], vif, accAi[hq][n]);
          accB [hq][n] = mfma16(pif[hq][kk], vrf, accB [hq][n]);
          accBi[hq][n] = mfma16(pif[hq][kk], vif, accBi[hq][n]);
        }
      }
    }
  }

  // ---- final denominator reduce (once, not per tile) ----
#pragma unroll
  for (int mm = 1; mm < 16; mm <<= 1)
#pragma unroll
    for (int hq = 0; hq < 2; ++hq)
#pragma unroll
      for (int t = 0; t < 4; ++t) {
        lpr[hq][t] += __shfl_xor(lpr[hq][t], mm);
        lpi[hq][t] += __shfl_xor(lpi[hq][t], mm);
      }

  // ---- epilogue ----
#pragma unroll
  for (int hq = 0; hq < 2; ++hq) {
    f32x4 ilr, ili;
#pragma unroll
    for (int t = 0; t < 4; ++t) { ilr[t] = 1.f / lpr[hq][t]; ili[t] = 1.f / lpi[hq][t]; }
#pragma unroll
    for (int n = 0; n < 4; ++n) {
      const int e = h * 64 + fr + 16 * n;
#pragma unroll
      for (int t = 0; t < 4; ++t) {
        const int sidx = qw + hq * 16 + g * 4 + t;
        const size_t o = ((size_t)b * S_LEN + sidx) * E_SZ + e;
        AOr[o] = f2bf(accA [hq][n][t] * ilr[t] - accBi[hq][n][t] * ili[t]);
        AOi[o] = f2bf(accAi[hq][n][t] * ilr[t] + accB [hq][n][t] * ili[t]);
      }
    }
  }
}

extern "C" void kernel_launch(void* const* d_in, const int* in_sizes, int n_in,
                              void* d_out, int out_size, void* d_ws, size_t ws_size,
                              hipStream_t stream)
{
    const float* query_r = (const float*)d_in[0];
    const float* query_i = (const float*)d_in[1];
    const float* key_r   = (const float*)d_in[2];
    const float* key_i   = (const float*)d_in[3];
    const float* value_r = (const float*)d_in[4];
    const float* value_i = (const float*)d_in[5];
    const float* wq_r = (const float*)d_in[6];
    const float* wq_i = (const float*)d_in[7];
    const float* bq_r = (const float*)d_in[8];
    const float* bq_i = (const float*)d_in[9];
    const float* wk_r = (const float*)d_in[10];
    const float* wk_i = (const float*)d_in[11];
    const float* bk_r = (const float*)d_in[12];
    const float* bk_i = (const float*)d_in[13];
    const float* wv_r = (const float*)d_in[14];
    const float* wv_i = (const float*)d_in[15];
    const float* bv_r = (const float*)d_in[16];
    const float* bv_i = (const float*)d_in[17];
    const float* wo_r = (const float*)d_in[18];
    const float* wo_i = (const float*)d_in[19];
    const float* bo_r = (const float*)d_in[20];
    const float* bo_i = (const float*)d_in[21];

    // ws: Q(2) K(2) Vt(2) [bf16 N1 each] | weights 8*WELEM bf16 | AO(2)  = 80 MiB
    ushort* ws   = (ushort*)d_ws;
    ushort* Qr   = ws;
    ushort* Qi   = Qr + (size_t)N1;
    ushort* Kr   = Qi + (size_t)N1;
    ushort* Ki   = Kr + (size_t)N1;
    ushort* Vtr  = Ki + (size_t)N1;
    ushort* Vti  = Vtr + (size_t)N1;
    ushort* Wb   = Vti + (size_t)N1;
    ushort* Wq_r = Wb + 0 * (size_t)WELEM;
    ushort* Wq_i = Wb + 1 * (size_t)WELEM;
    ushort* Wk_r = Wb + 2 * (size_t)WELEM;
    ushort* Wk_i = Wb + 3 * (size_t)WELEM;
    ushort* Wv_r = Wb + 4 * (size_t)WELEM;
    ushort* Wv_i = Wb + 5 * (size_t)WELEM;
    ushort* Wo_r = Wb + 6 * (size_t)WELEM;
    ushort* Wo_i = Wb + 7 * (size_t)WELEM;
    ushort* AOr  = Wb + 8 * (size_t)WELEM;
    ushort* AOi  = AOr + (size_t)N1;

    // bf16 activation staging lives in d_out (33.5 MB; we use 16 MB).
    // d_out is scratch until the final cgemm<2> overwrites all of it.
    ushort* Xsr = (ushort*)d_out;
    ushort* Xsi = Xsr + (size_t)N1;

    cast_w8<<<8192, 256, 0, stream>>>(wq_r, wq_i, wk_r, wk_i,
                                      wv_r, wv_i, wo_r, wo_i, Wb);

    dim3 gg(16, 32);   // 512 workgroups, BN=64, BM=128

    castA<<<2048, 256, 0, stream>>>(query_r, query_i, Xsr, Xsi);
    cgemm<0><<<gg, 256, 0, stream>>>(Xsr, Xsi, Wq_r, Wq_i, bq_r, bq_i,
                                     Qr, Qi, nullptr, 0.125f);
    castA<<<2048, 256, 0, stream>>>(key_r, key_i, Xsr, Xsi);
    cgemm<0><<<gg, 256, 0, stream>>>(Xsr, Xsi, Wk_r, Wk_i, bk_r, bk_i,
                                     Kr, Ki, nullptr, 1.0f);
    castA<<<2048, 256, 0, stream>>>(value_r, value_i, Xsr, Xsi);
    cgemm<1><<<gg, 256, 0, stream>>>(Xsr, Xsi, Wv_r, Wv_i, bv_r, bv_i,
                                     Vtr, Vti, nullptr, 1.0f);

    cattn_mfma<<<dim3(S_LEN / 128, B_SZ * H_CNT), 256, 0, stream>>>(
        Qr, Qi, Kr, Ki, Vtr, Vti, AOr, AOi);

    cgemm<2><<<gg, 256, 0, stream>>>(AOr, AOi, Wo_r, Wo_i, bo_r, bo_i,
                                     nullptr, nullptr, (float*)d_out, 1.0f);
}